// Round 1
// baseline (1830.911 us; speedup 1.0000x reference)
//
#include <hip/hip_runtime.h>
#include <math.h>

constexpr int NA   = 16000;
constexpr int NE   = 256000;
constexpr int F    = 128;
constexpr int NF   = 32;
constexpr int NRBF = 20;
constexpr float CUTOFF       = 5.0f;
constexpr float INV_SQRT_F   = 0.0883883476483184f;  // 1/sqrt(128)
constexpr float INV_SQRT_2NF = 0.125f;               // 1/sqrt(64)
constexpr float INV_SQ3      = 0.5773502691896258f;
constexpr float SQ3          = 1.7320508075688772f;
constexpr float LOG2_        = 0.6931471805599453f;
constexpr float PI_          = 3.14159265358979323f;

__device__ __forceinline__ float ssp(float x) {
    // softplus(x) - log(2), numerically stable
    return fmaxf(x, 0.0f) + log1pf(expf(-fabsf(x))) - LOG2_;
}

// ---------------------------------------------------------------- K0: per-edge geometry
__global__ void geom_kernel(const float* __restrict__ r_ij,
                            float* __restrict__ fij,
                            float* __restrict__ rcut,
                            float* __restrict__ yv) {
    int e = blockIdx.x * blockDim.x + threadIdx.x;
    if (e >= NE) return;
    float x = r_ij[3*e+0], y = r_ij[3*e+1], z = r_ij[3*e+2];
    float d = sqrtf(x*x + y*y + z*z);
    const float delta = CUTOFF / (NRBF - 1);
    const float coeff = -0.5f / (delta * delta);
    #pragma unroll
    for (int k = 0; k < NRBF; k++) {
        float t = d - delta * (float)k;
        fij[e*NRBF + k] = expf(coeff * t * t);
    }
    float rc = 0.5f * (cosf(PI_ * d / CUTOFF) + 1.0f);
    rcut[e] = (d < CUTOFF) ? rc : 0.0f;
    float inv = SQ3 / fmaxf(d, 1e-9f);
    yv[3*e+0] = x * inv;
    yv[3*e+1] = y * inv;
    yv[3*e+2] = z * inv;
}

// ---------------------------------------------------------------- K1: segment offsets (idx_i sorted)
__global__ void offsets_kernel(const int* __restrict__ idx_i, int* __restrict__ offs) {
    int n = blockIdx.x * blockDim.x + threadIdx.x;
    if (n > NA) return;
    int lo = 0, hi = NE;
    while (lo < hi) {
        int mid = (lo + hi) >> 1;
        if (idx_i[mid] < n) lo = mid + 1; else hi = mid;
    }
    offs[n] = lo;
}

// ---------------------------------------------------------------- K2: xs = emb[Z] @ W_pe * inv_sqrt_F
__global__ void embed_kernel(const int* __restrict__ Z,
                             const float* __restrict__ emb,
                             const float* __restrict__ Wpe,
                             float* __restrict__ xs) {
    __shared__ float er[F];
    int n = blockIdx.x, t = threadIdx.x;
    int z = Z[n];
    er[t] = emb[z*F + t];
    __syncthreads();
    float acc = 0.0f;
    #pragma unroll 8
    for (int k = 0; k < F; k++) acc += er[k] * Wpe[k*F + t];
    xs[n*F + t] = acc * INV_SQRT_F;
}

// ---------------------------------------------------------------- K3: hs = xs@W0s*inv, hv = xv@W0v*inv
__global__ void h_kernel(const float* __restrict__ xs,
                         const float* __restrict__ xv,
                         const float* __restrict__ W0s,
                         const float* __restrict__ W0v,
                         float* __restrict__ hs,
                         float* __restrict__ hv) {
    __shared__ float sxs[F];
    __shared__ float sxv[F*3];
    int n = blockIdx.x, t = threadIdx.x;   // 128 threads
    sxs[t] = xs[n*F + t];
    sxv[t]       = xv[n*F*3 + t];
    sxv[t + 128] = xv[n*F*3 + t + 128];
    sxv[t + 256] = xv[n*F*3 + t + 256];
    __syncthreads();
    int g = t & 31, sel = t >> 5;
    float acc = 0.0f;
    if (sel == 0) {
        #pragma unroll 8
        for (int k = 0; k < F; k++) acc += sxs[k] * W0s[k*NF + g];
        hs[n*NF + g] = acc * INV_SQRT_F;
    } else {
        int c = sel - 1;
        #pragma unroll 8
        for (int k = 0; k < F; k++) acc += sxv[k*3 + c] * W0v[k*NF + g];
        hv[n*NF*3 + g*3 + c] = acc * INV_SQRT_F;
    }
}

// ---------------------------------------------------------------- K4: per-atom edge aggregation + atom MLP
__global__ void agg_kernel(const int* __restrict__ idx_j,
                           const int* __restrict__ offs,
                           const float* __restrict__ fijg,
                           const float* __restrict__ rcutg,
                           const float* __restrict__ yvg,
                           const float* __restrict__ hs,
                           const float* __restrict__ hv,
                           const float* __restrict__ Wf1,
                           const float* __restrict__ bf1,
                           const float* __restrict__ Wf2,
                           const float* __restrict__ bf2,
                           const float* __restrict__ As,
                           const float* __restrict__ Av,
                           const float* __restrict__ Bs,
                           const float* __restrict__ Bv,
                           float* __restrict__ xs,
                           float* __restrict__ xv) {
    __shared__ float sj[NF];
    __shared__ float vj[NF*3];
    __shared__ float h1[NF];
    __shared__ float Wrow[6*NF];
    __shared__ float fij[NRBF];
    __shared__ float yv[3];
    __shared__ float srcut;
    __shared__ float agg[256];
    __shared__ float os1[F];
    __shared__ float ov1[F*3];

    int n = blockIdx.x, t = threadIdx.x;   // 256 threads
    int e0 = offs[n], e1 = offs[n+1];

    // column mapping for the accumulate phase
    int f_a = 0, c_a = 0;
    if (t >= 160)      { int u = t - 160; f_a = u / 3; c_a = u - 3*f_a; }
    else if (t >= 64)  { int u = t - 64;  f_a = u / 3; c_a = u - 3*f_a; }

    float acc = 0.0f;
    for (int e = e0; e < e1; e++) {
        int j = idx_j[e];
        if (t < 32)                sj[t] = hs[j*NF + t];
        else if (t < 128)          vj[t-32] = hv[j*NF*3 + (t-32)];
        else if (t < 128+NRBF)     fij[t-128] = fijg[e*NRBF + (t-128)];
        else if (t < 151)          yv[t-148] = yvg[e*3 + (t-148)];
        else if (t == 151)         srcut = rcutg[e];
        __syncthreads();
        if (t < NF) {
            float a = bf1[t];
            #pragma unroll
            for (int k = 0; k < NRBF; k++) a += fij[k] * Wf1[k*NF + t];
            h1[t] = ssp(a);
        }
        __syncthreads();
        if (t < 6*NF) {
            float a = bf2[t];
            #pragma unroll 8
            for (int k = 0; k < NF; k++) a += h1[k] * Wf2[k*6*NF + t];
            Wrow[t] = a * srcut;
        }
        __syncthreads();
        float val;
        if (t < 32)       val = sj[t] * Wrow[t];
        else if (t < 64)  { int f = t - 32;
                            val = (vj[f*3]*yv[0] + vj[f*3+1]*yv[1] + vj[f*3+2]*yv[2]) * INV_SQ3 * Wrow[32+f]; }
        else if (t < 160)   val = sj[f_a] * yv[c_a] * Wrow[64+f_a];
        else                val = vj[f_a*3 + c_a] * Wrow[96+f_a];
        acc += val;
        __syncthreads();
    }
    agg[t] = acc;
    __syncthreads();

    // ---- atom-side MLP ----
    // s_in = agg[0:64]; v_in[k][c] = agg[64 + 3k + c], k in [0,64)
    if (t < F) {
        float a = 0.0f;
        #pragma unroll 8
        for (int k = 0; k < 2*NF; k++) a += agg[k] * As[k*F + t];
        os1[t] = ssp(a * INV_SQRT_2NF);
        float b = 0.0f;
        #pragma unroll 8
        for (int k = 0; k < 2*NF; k++) b += agg[64 + 3*k + 0] * Av[k*F + t];
        ov1[t*3 + 0] = b * INV_SQRT_2NF;
    } else {
        int j = t - F;
        float b1 = 0.0f, b2 = 0.0f;
        #pragma unroll 8
        for (int k = 0; k < 2*NF; k++) {
            float w = Av[k*F + j];
            b1 += agg[64 + 3*k + 1] * w;
            b2 += agg[64 + 3*k + 2] * w;
        }
        ov1[j*3 + 1] = b1 * INV_SQRT_2NF;
        ov1[j*3 + 2] = b2 * INV_SQRT_2NF;
    }
    __syncthreads();
    if (t < F) {
        float a = 0.0f;
        #pragma unroll 8
        for (int k = 0; k < F; k++) a += os1[k] * Bs[k*F + t];
        xs[n*F + t] += a * INV_SQRT_F;
        float b = 0.0f;
        #pragma unroll 8
        for (int k = 0; k < F; k++) b += ov1[k*3 + 0] * Bv[k*F + t];
        xv[n*F*3 + t*3 + 0] += b * INV_SQRT_F;
    } else {
        int j = t - F;
        float b1 = 0.0f, b2 = 0.0f;
        #pragma unroll 8
        for (int k = 0; k < F; k++) {
            float w = Bv[k*F + j];
            b1 += ov1[k*3 + 1] * w;
            b2 += ov1[k*3 + 2] * w;
        }
        xv[n*F*3 + j*3 + 1] += b1 * INV_SQRT_F;
        xv[n*F*3 + j*3 + 2] += b2 * INV_SQRT_F;
    }
}

// ----------------------------------------------------------------
extern "C" void kernel_launch(void* const* d_in, const int* in_sizes, int n_in,
                              void* d_out, int out_size, void* d_ws, size_t ws_size,
                              hipStream_t stream) {
    (void)in_sizes; (void)n_in; (void)out_size; (void)ws_size;
    const int*   Z     = (const int*)  d_in[0];
    const float* r_ij  = (const float*)d_in[1];
    const int*   idx_i = (const int*)  d_in[2];
    const int*   idx_j = (const int*)  d_in[3];
    const float* emb   = (const float*)d_in[4];
    const float* Wpe   = (const float*)d_in[5];
    const float* W0s   = (const float*)d_in[6];
    const float* W0v   = (const float*)d_in[7];
    const float* Wf1   = (const float*)d_in[8];
    const float* bf1   = (const float*)d_in[9];
    const float* Wf2   = (const float*)d_in[10];
    const float* bf2   = (const float*)d_in[11];
    const float* As    = (const float*)d_in[12];
    const float* Av    = (const float*)d_in[13];
    const float* Bs    = (const float*)d_in[14];
    const float* Bv    = (const float*)d_in[15];

    float* xs = (float*)d_out;           // xs lives in d_out (updated in place)
    float* ws = (float*)d_ws;
    float* fij  = ws;                    // NE*20
    float* rcut = fij  + (size_t)NE*NRBF;// NE
    float* yv   = rcut + NE;             // NE*3
    float* xv   = yv   + (size_t)NE*3;   // NA*384
    float* hs   = xv   + (size_t)NA*F*3; // NA*32
    float* hv   = hs   + (size_t)NA*NF;  // NA*96
    int*   offs = (int*)(hv + (size_t)NA*NF*3); // NA+1

    hipMemsetAsync(xv, 0, (size_t)NA*F*3*sizeof(float), stream);

    geom_kernel<<<(NE+255)/256, 256, 0, stream>>>(r_ij, fij, rcut, yv);
    offsets_kernel<<<(NA+256)/256, 256, 0, stream>>>(idx_i, offs);
    embed_kernel<<<NA, F, 0, stream>>>(Z, emb, Wpe, xs);

    for (int l = 0; l < 3; l++) {
        h_kernel<<<NA, F, 0, stream>>>(xs, xv,
                                       W0s + (size_t)l*F*NF, W0v + (size_t)l*F*NF,
                                       hs, hv);
        agg_kernel<<<NA, 256, 0, stream>>>(idx_j, offs, fij, rcut, yv, hs, hv,
                                           Wf1 + (size_t)l*NRBF*NF, bf1 + (size_t)l*NF,
                                           Wf2 + (size_t)l*NF*6*NF, bf2 + (size_t)l*6*NF,
                                           As  + (size_t)l*2*NF*F,  Av  + (size_t)l*2*NF*F,
                                           Bs  + (size_t)l*F*F,     Bv  + (size_t)l*F*F,
                                           xs, xv);
    }
}

// Round 2
// 1672.059 us; speedup vs baseline: 1.0950x; 1.0950x over previous
//
#include <hip/hip_runtime.h>
#include <math.h>

constexpr int NA   = 16000;
constexpr int NE   = 256000;
constexpr int F    = 128;
constexpr int NF   = 32;
constexpr int NRBF = 20;
constexpr int EB   = 8;     // edges per barrier round
constexpr float CUTOFF       = 5.0f;
constexpr float INV_SQRT_F   = 0.0883883476483184f;  // 1/sqrt(128)
constexpr float INV_SQRT_2NF = 0.125f;               // 1/sqrt(64)
constexpr float INV_SQ3      = 0.5773502691896258f;
constexpr float SQ3          = 1.7320508075688772f;
constexpr float LOG2_        = 0.6931471805599453f;
constexpr float PI_          = 3.14159265358979323f;

__device__ __forceinline__ float ssp(float x) {
    return fmaxf(x, 0.0f) + log1pf(expf(-fabsf(x))) - LOG2_;
}

// ---------------------------------------------------------------- K0: per-edge geometry
__global__ void geom_kernel(const float* __restrict__ r_ij,
                            float* __restrict__ fij,
                            float* __restrict__ rcut,
                            float* __restrict__ yv) {
    int e = blockIdx.x * blockDim.x + threadIdx.x;
    if (e >= NE) return;
    float x = r_ij[3*e+0], y = r_ij[3*e+1], z = r_ij[3*e+2];
    float d = sqrtf(x*x + y*y + z*z);
    const float delta = CUTOFF / (NRBF - 1);
    const float coeff = -0.5f / (delta * delta);
    #pragma unroll
    for (int k = 0; k < NRBF; k++) {
        float t = d - delta * (float)k;
        fij[e*NRBF + k] = expf(coeff * t * t);
    }
    float rc = 0.5f * (cosf(PI_ * d / CUTOFF) + 1.0f);
    rcut[e] = (d < CUTOFF) ? rc : 0.0f;
    float inv = SQ3 / fmaxf(d, 1e-9f);
    yv[3*e+0] = x * inv;
    yv[3*e+1] = y * inv;
    yv[3*e+2] = z * inv;
}

// ---------------------------------------------------------------- K1: segment offsets (idx_i sorted)
__global__ void offsets_kernel(const int* __restrict__ idx_i, int* __restrict__ offs) {
    int n = blockIdx.x * blockDim.x + threadIdx.x;
    if (n > NA) return;
    int lo = 0, hi = NE;
    while (lo < hi) {
        int mid = (lo + hi) >> 1;
        if (idx_i[mid] < n) lo = mid + 1; else hi = mid;
    }
    offs[n] = lo;
}

// ---------------------------------------------------------------- K2: xs = emb[Z] @ W_pe * inv_sqrt_F
__global__ void embed_kernel(const int* __restrict__ Z,
                             const float* __restrict__ emb,
                             const float* __restrict__ Wpe,
                             float* __restrict__ xs) {
    __shared__ float er[F];
    int n = blockIdx.x, t = threadIdx.x;
    int z = Z[n];
    er[t] = emb[z*F + t];
    __syncthreads();
    float acc = 0.0f;
    #pragma unroll 8
    for (int k = 0; k < F; k++) acc += er[k] * Wpe[k*F + t];
    xs[n*F + t] = acc * INV_SQRT_F;
}

// ---------------------------------------------------------------- K3: hs = xs@W0s*inv, hv = xv@W0v*inv
__global__ void h_kernel(const float* __restrict__ xs,
                         const float* __restrict__ xv,
                         const float* __restrict__ W0s,
                         const float* __restrict__ W0v,
                         float* __restrict__ hs,
                         float* __restrict__ hv) {
    __shared__ float sxs[F];
    __shared__ float sxv[F*3];
    int n = blockIdx.x, t = threadIdx.x;   // 128 threads
    sxs[t] = xs[n*F + t];
    sxv[t]       = xv[n*F*3 + t];
    sxv[t + 128] = xv[n*F*3 + t + 128];
    sxv[t + 256] = xv[n*F*3 + t + 256];
    __syncthreads();
    int g = t & 31, sel = t >> 5;
    float acc = 0.0f;
    if (sel == 0) {
        #pragma unroll 8
        for (int k = 0; k < F; k++) acc += sxs[k] * W0s[k*NF + g];
        hs[n*NF + g] = acc * INV_SQRT_F;
    } else {
        int c = sel - 1;
        #pragma unroll 8
        for (int k = 0; k < F; k++) acc += sxv[k*3 + c] * W0v[k*NF + g];
        hv[n*NF*3 + g*3 + c] = acc * INV_SQRT_F;
    }
}

// ---------------------------------------------------------------- K4: per-atom edge aggregation + atom MLP
// 8 edges per barrier round: 4 barriers / 8 edges instead of 3 / edge.
__global__ void agg_kernel(const int* __restrict__ idx_j,
                           const int* __restrict__ offs,
                           const float* __restrict__ fijg,
                           const float* __restrict__ rcutg,
                           const float* __restrict__ yvg,
                           const float* __restrict__ hs,
                           const float* __restrict__ hv,
                           const float* __restrict__ Wf1,
                           const float* __restrict__ bf1,
                           const float* __restrict__ Wf2,
                           const float* __restrict__ bf2,
                           const float* __restrict__ As,
                           const float* __restrict__ Av,
                           const float* __restrict__ Bs,
                           const float* __restrict__ Bv,
                           float* __restrict__ xs,
                           float* __restrict__ xv) {
    __shared__ float se[EB][NF];
    __shared__ float ve[EB][NF*3];
    __shared__ float fe[EB][NRBF];
    __shared__ float ye[EB][4];       // yv0,yv1,yv2,rcut
    __shared__ float h1[EB][NF];
    __shared__ float Wr[EB][6*NF];
    __shared__ float agg[256];
    __shared__ float os1[F];
    __shared__ float ov1[F*3];

    int n = blockIdx.x, t = threadIdx.x;   // 256 threads
    int e0 = offs[n], e1 = offs[n+1];

    // column mapping for the accumulate phase (constant per thread)
    int f_a = 0, c_a = 0;
    if (t >= 160)      { int u = t - 160; f_a = u / 3; c_a = u - 3*f_a; }
    else if (t >= 64)  { int u = t - 64;  f_a = u / 3; c_a = u - 3*f_a; }

    int s_t = t >> 5, g_t = t & 31;        // staging / h1 mapping

    float acc = 0.0f;
    for (int base = e0; base < e1; base += EB) {
        int nE = min(EB, e1 - base);
        // ---- stage 8 edges ----
        if (s_t < nE) {
            int e = base + s_t;
            int j = idx_j[e];
            se[s_t][g_t]      = hs[j*NF + g_t];
            ve[s_t][g_t]      = hv[j*96 + g_t];
            ve[s_t][g_t + 32] = hv[j*96 + g_t + 32];
            ve[s_t][g_t + 64] = hv[j*96 + g_t + 64];
        }
        if (t < 160) {
            int s2 = t / 20, k = t - s2*20;
            if (s2 < nE) fe[s2][k] = fijg[(size_t)(base+s2)*NRBF + k];
        } else if (t < 192) {
            int u = t - 160; int s2 = u >> 2, c = u & 3;
            if (s2 < nE) ye[s2][c] = (c < 3) ? yvg[(base+s2)*3 + c] : rcutg[base+s2];
        }
        __syncthreads();
        // ---- filter MLP layer 1: h1[s][g] (one output per thread) ----
        if (s_t < nE) {
            float a = bf1[g_t];
            #pragma unroll
            for (int k = 0; k < NRBF; k++) a += fe[s_t][k] * Wf1[k*NF + g_t];
            h1[s_t][g_t] = ssp(a);
        }
        __syncthreads();
        // ---- filter MLP layer 2: Wr[s][c] (6 outputs per thread) ----
        #pragma unroll
        for (int u = 0; u < 6; u++) {
            int idx = u*256 + t;
            int s2 = idx / 192, c = idx - s2*192;
            if (s2 < nE) {
                float a = bf2[c];
                #pragma unroll 8
                for (int k = 0; k < NF; k++) a += h1[s2][k] * Wf2[k*(6*NF) + c];
                Wr[s2][c] = a * ye[s2][3];
            }
        }
        __syncthreads();
        // ---- accumulate column t over the staged edges ----
        for (int s2 = 0; s2 < nE; s2++) {
            float val;
            if (t < 32)       val = se[s2][t] * Wr[s2][t];
            else if (t < 64)  { int f = t - 32;
                                val = (ve[s2][f*3]*ye[s2][0] + ve[s2][f*3+1]*ye[s2][1] + ve[s2][f*3+2]*ye[s2][2]) * INV_SQ3 * Wr[s2][32+f]; }
            else if (t < 160)   val = se[s2][f_a] * ye[s2][c_a] * Wr[s2][64+f_a];
            else                val = ve[s2][f_a*3 + c_a] * Wr[s2][96+f_a];
            acc += val;
        }
        __syncthreads();
    }
    agg[t] = acc;
    __syncthreads();

    // ---- atom-side MLP ----
    if (t < F) {
        float a = 0.0f;
        #pragma unroll 8
        for (int k = 0; k < 2*NF; k++) a += agg[k] * As[k*F + t];
        os1[t] = ssp(a * INV_SQRT_2NF);
        float b = 0.0f;
        #pragma unroll 8
        for (int k = 0; k < 2*NF; k++) b += agg[64 + 3*k + 0] * Av[k*F + t];
        ov1[t*3 + 0] = b * INV_SQRT_2NF;
    } else {
        int j = t - F;
        float b1 = 0.0f, b2 = 0.0f;
        #pragma unroll 8
        for (int k = 0; k < 2*NF; k++) {
            float w = Av[k*F + j];
            b1 += agg[64 + 3*k + 1] * w;
            b2 += agg[64 + 3*k + 2] * w;
        }
        ov1[j*3 + 1] = b1 * INV_SQRT_2NF;
        ov1[j*3 + 2] = b2 * INV_SQRT_2NF;
    }
    __syncthreads();
    if (t < F) {
        float a = 0.0f;
        #pragma unroll 8
        for (int k = 0; k < F; k++) a += os1[k] * Bs[k*F + t];
        xs[n*F + t] += a * INV_SQRT_F;
        float b = 0.0f;
        #pragma unroll 8
        for (int k = 0; k < F; k++) b += ov1[k*3 + 0] * Bv[k*F + t];
        xv[n*F*3 + t*3 + 0] += b * INV_SQRT_F;
    } else {
        int j = t - F;
        float b1 = 0.0f, b2 = 0.0f;
        #pragma unroll 8
        for (int k = 0; k < F; k++) {
            float w = Bv[k*F + j];
            b1 += ov1[k*3 + 1] * w;
            b2 += ov1[k*3 + 2] * w;
        }
        xv[n*F*3 + j*3 + 1] += b1 * INV_SQRT_F;
        xv[n*F*3 + j*3 + 2] += b2 * INV_SQRT_F;
    }
}

// ----------------------------------------------------------------
extern "C" void kernel_launch(void* const* d_in, const int* in_sizes, int n_in,
                              void* d_out, int out_size, void* d_ws, size_t ws_size,
                              hipStream_t stream) {
    (void)in_sizes; (void)n_in; (void)out_size; (void)ws_size;
    const int*   Z     = (const int*)  d_in[0];
    const float* r_ij  = (const float*)d_in[1];
    const int*   idx_i = (const int*)  d_in[2];
    const int*   idx_j = (const int*)  d_in[3];
    const float* emb   = (const float*)d_in[4];
    const float* Wpe   = (const float*)d_in[5];
    const float* W0s   = (const float*)d_in[6];
    const float* W0v   = (const float*)d_in[7];
    const float* Wf1   = (const float*)d_in[8];
    const float* bf1   = (const float*)d_in[9];
    const float* Wf2   = (const float*)d_in[10];
    const float* bf2   = (const float*)d_in[11];
    const float* As    = (const float*)d_in[12];
    const float* Av    = (const float*)d_in[13];
    const float* Bs    = (const float*)d_in[14];
    const float* Bv    = (const float*)d_in[15];

    float* xs = (float*)d_out;
    float* ws = (float*)d_ws;
    float* fij  = ws;                    // NE*20
    float* rcut = fij  + (size_t)NE*NRBF;// NE
    float* yv   = rcut + NE;             // NE*3
    float* xv   = yv   + (size_t)NE*3;   // NA*384
    float* hs   = xv   + (size_t)NA*F*3; // NA*32
    float* hv   = hs   + (size_t)NA*NF;  // NA*96
    int*   offs = (int*)(hv + (size_t)NA*NF*3); // NA+1

    hipMemsetAsync(xv, 0, (size_t)NA*F*3*sizeof(float), stream);

    geom_kernel<<<(NE+255)/256, 256, 0, stream>>>(r_ij, fij, rcut, yv);
    offsets_kernel<<<(NA+256)/256, 256, 0, stream>>>(idx_i, offs);
    embed_kernel<<<NA, F, 0, stream>>>(Z, emb, Wpe, xs);

    for (int l = 0; l < 3; l++) {
        h_kernel<<<NA, F, 0, stream>>>(xs, xv,
                                       W0s + (size_t)l*F*NF, W0v + (size_t)l*F*NF,
                                       hs, hv);
        agg_kernel<<<NA, 256, 0, stream>>>(idx_j, offs, fij, rcut, yv, hs, hv,
                                           Wf1 + (size_t)l*NRBF*NF, bf1 + (size_t)l*NF,
                                           Wf2 + (size_t)l*NF*6*NF, bf2 + (size_t)l*6*NF,
                                           As  + (size_t)l*2*NF*F,  Av  + (size_t)l*2*NF*F,
                                           Bs  + (size_t)l*F*F,     Bv  + (size_t)l*F*F,
                                           xs, xv);
    }
}

// Round 3
// 1264.086 us; speedup vs baseline: 1.4484x; 1.3227x over previous
//
#include <hip/hip_runtime.h>
#include <math.h>

constexpr int NA   = 16000;
constexpr int NE   = 256000;
constexpr int F    = 128;
constexpr int NF   = 32;
constexpr int NRBF = 20;
constexpr int EB   = 8;     // edges per barrier round
constexpr float CUTOFF       = 5.0f;
constexpr float INV_SQRT_F   = 0.0883883476483184f;  // 1/sqrt(128)
constexpr float INV_SQRT_2NF = 0.125f;               // 1/sqrt(64)
constexpr float INV_SQ3      = 0.5773502691896258f;
constexpr float SQ3          = 1.7320508075688772f;
constexpr float LOG2_        = 0.6931471805599453f;
constexpr float PI_          = 3.14159265358979323f;

__device__ __forceinline__ float ssp(float x) {
    // softplus(x) - log(2) with fast hw transcendentals (abs err ~1e-6, threshold 0.1)
    return fmaxf(x, 0.0f) + __logf(1.0f + __expf(-fabsf(x))) - LOG2_;
}

// ---------------------------------------------------------------- K0: per-edge geometry
__global__ void geom_kernel(const float* __restrict__ r_ij,
                            float* __restrict__ fij,
                            float* __restrict__ rcut,
                            float* __restrict__ yv) {
    int e = blockIdx.x * blockDim.x + threadIdx.x;
    if (e >= NE) return;
    float x = r_ij[3*e+0], y = r_ij[3*e+1], z = r_ij[3*e+2];
    float d = sqrtf(x*x + y*y + z*z);
    const float delta = CUTOFF / (NRBF - 1);
    const float coeff = -0.5f / (delta * delta);
    #pragma unroll
    for (int k = 0; k < NRBF; k++) {
        float t = d - delta * (float)k;
        fij[e*NRBF + k] = __expf(coeff * t * t);
    }
    float rc = 0.5f * (__cosf(PI_ * d / CUTOFF) + 1.0f);
    rcut[e] = (d < CUTOFF) ? rc : 0.0f;
    float inv = SQ3 / fmaxf(d, 1e-9f);
    yv[3*e+0] = x * inv;
    yv[3*e+1] = y * inv;
    yv[3*e+2] = z * inv;
}

// ---------------------------------------------------------------- K1: segment offsets (idx_i sorted)
__global__ void offsets_kernel(const int* __restrict__ idx_i, int* __restrict__ offs) {
    int n = blockIdx.x * blockDim.x + threadIdx.x;
    if (n > NA) return;
    int lo = 0, hi = NE;
    while (lo < hi) {
        int mid = (lo + hi) >> 1;
        if (idx_i[mid] < n) lo = mid + 1; else hi = mid;
    }
    offs[n] = lo;
}

// ---------------------------------------------------------------- K2: xs = emb[Z] @ W_pe * inv_sqrt_F
__global__ void embed_kernel(const int* __restrict__ Z,
                             const float* __restrict__ emb,
                             const float* __restrict__ Wpe,
                             float* __restrict__ xs) {
    __shared__ float er[F];
    int n = blockIdx.x, t = threadIdx.x;
    int z = Z[n];
    er[t] = emb[z*F + t];
    __syncthreads();
    float acc = 0.0f;
    #pragma unroll 8
    for (int k = 0; k < F; k++) acc += er[k] * Wpe[k*F + t];
    xs[n*F + t] = acc * INV_SQRT_F;
}

// ---------------------------------------------------------------- K3: hs = xs@W0s*inv, hv = xv@W0v*inv
__global__ void h_kernel(const float* __restrict__ xs,
                         const float* __restrict__ xv,
                         const float* __restrict__ W0s,
                         const float* __restrict__ W0v,
                         float* __restrict__ hs,
                         float* __restrict__ hv) {
    __shared__ float sxs[F];
    __shared__ float sxv[F*3];
    int n = blockIdx.x, t = threadIdx.x;   // 128 threads
    sxs[t] = xs[n*F + t];
    sxv[t]       = xv[n*F*3 + t];
    sxv[t + 128] = xv[n*F*3 + t + 128];
    sxv[t + 256] = xv[n*F*3 + t + 256];
    __syncthreads();
    int g = t & 31, sel = t >> 5;
    float acc = 0.0f;
    if (sel == 0) {
        #pragma unroll 8
        for (int k = 0; k < F; k++) acc += sxs[k] * W0s[k*NF + g];
        hs[n*NF + g] = acc * INV_SQRT_F;
    } else {
        int c = sel - 1;
        #pragma unroll 8
        for (int k = 0; k < F; k++) acc += sxv[k*3 + c] * W0v[k*NF + g];
        hv[n*NF*3 + g*3 + c] = acc * INV_SQRT_F;
    }
}

// ---------------------------------------------------------------- K4: per-atom edge aggregation + atom MLP
// Only the 128 live W columns (w0a,w0b,w1a,w1b); filter weights register-resident.
__global__ __launch_bounds__(256, 4)
void agg_kernel(const int* __restrict__ idx_j,
                const int* __restrict__ offs,
                const float* __restrict__ fijg,
                const float* __restrict__ rcutg,
                const float* __restrict__ yvg,
                const float* __restrict__ hs,
                const float* __restrict__ hv,
                const float* __restrict__ Wf1,
                const float* __restrict__ bf1,
                const float* __restrict__ Wf2,
                const float* __restrict__ bf2,
                const float* __restrict__ As,
                const float* __restrict__ Av,
                const float* __restrict__ Bs,
                const float* __restrict__ Bv,
                float* __restrict__ xs,
                float* __restrict__ xv) {
    __shared__ float se[EB][NF];
    __shared__ float ve[EB][NF*3];
    __shared__ float fe[EB][NRBF];
    __shared__ float ye[EB][4];       // yv0,yv1,yv2,rcut
    __shared__ float h1[EB][NF];
    __shared__ float Wr[EB][128];
    __shared__ float agg[256];
    __shared__ float os1[F];
    __shared__ float ov1[F*3];

    int n = blockIdx.x, t = threadIdx.x;   // 256 threads
    int e0 = offs[n], e1 = offs[n+1];

    // column mapping for the accumulate phase (constant per thread)
    int f_a = 0, c_a = 0;
    if (t >= 160)      { int u = t - 160; f_a = u / 3; c_a = u - 3*f_a; }
    else if (t >= 64)  { int u = t - 64;  f_a = u / 3; c_a = u - 3*f_a; }

    int s_t = t >> 5, g_t = t & 31;        // staging / h1 mapping
    int c_w = t & 127, sb_w = (t >> 7) * 4; // Wr mapping: column c_w, edges sb_w..sb_w+3

    // ---- hoist filter weights into registers (uniform per thread, reused every round)
    float wf1[NRBF];
    #pragma unroll
    for (int k = 0; k < NRBF; k++) wf1[k] = Wf1[k*NF + g_t];
    float bf1c = bf1[g_t];
    float wf2[NF];
    #pragma unroll
    for (int k = 0; k < NF; k++) wf2[k] = Wf2[k*(6*NF) + c_w];
    float bf2c = bf2[c_w];

    float acc = 0.0f;
    for (int base = e0; base < e1; base += EB) {
        int nE = min(EB, e1 - base);
        // ---- stage up to 8 edges ----
        if (s_t < nE) {
            int e = base + s_t;
            int j = idx_j[e];
            se[s_t][g_t]      = hs[j*NF + g_t];
            ve[s_t][g_t]      = hv[j*96 + g_t];
            ve[s_t][g_t + 32] = hv[j*96 + g_t + 32];
            ve[s_t][g_t + 64] = hv[j*96 + g_t + 64];
        }
        if (t < 160) {
            int s2 = t / 20, k = t - s2*20;
            if (s2 < nE) fe[s2][k] = fijg[(size_t)(base+s2)*NRBF + k];
        } else if (t < 192) {
            int u = t - 160; int s2 = u >> 2, c = u & 3;
            if (s2 < nE) ye[s2][c] = (c < 3) ? yvg[(base+s2)*3 + c] : rcutg[base+s2];
        }
        __syncthreads();
        // ---- filter MLP layer 1: h1[s][g] (one output per thread, reg weights) ----
        if (s_t < nE) {
            float a = bf1c;
            #pragma unroll
            for (int k = 0; k < NRBF; k++) a += fe[s_t][k] * wf1[k];
            h1[s_t][g_t] = ssp(a);
        }
        __syncthreads();
        // ---- filter MLP layer 2: thread owns column c_w for 4 edges, reg weights ----
        #pragma unroll
        for (int u = 0; u < 4; u++) {
            int s2 = sb_w + u;
            if (s2 < nE) {
                float a = bf2c;
                #pragma unroll 8
                for (int k = 0; k < NF; k++) a += h1[s2][k] * wf2[k];
                Wr[s2][c_w] = a * ye[s2][3];
            }
        }
        __syncthreads();
        // ---- accumulate column t over the staged edges ----
        for (int s2 = 0; s2 < nE; s2++) {
            float val;
            if (t < 32)       val = se[s2][t] * Wr[s2][t];
            else if (t < 64)  { int f = t - 32;
                                val = (ve[s2][f*3]*ye[s2][0] + ve[s2][f*3+1]*ye[s2][1] + ve[s2][f*3+2]*ye[s2][2]) * INV_SQ3 * Wr[s2][32+f]; }
            else if (t < 160)   val = se[s2][f_a] * ye[s2][c_a] * Wr[s2][64+f_a];
            else                val = ve[s2][f_a*3 + c_a] * Wr[s2][96+f_a];
            acc += val;
        }
        __syncthreads();
    }
    agg[t] = acc;
    __syncthreads();

    // ---- atom-side MLP ----
    if (t < F) {
        float a = 0.0f;
        #pragma unroll 8
        for (int k = 0; k < 2*NF; k++) a += agg[k] * As[k*F + t];
        os1[t] = ssp(a * INV_SQRT_2NF);
        float b = 0.0f;
        #pragma unroll 8
        for (int k = 0; k < 2*NF; k++) b += agg[64 + 3*k + 0] * Av[k*F + t];
        ov1[t*3 + 0] = b * INV_SQRT_2NF;
    } else {
        int j = t - F;
        float b1 = 0.0f, b2 = 0.0f;
        #pragma unroll 8
        for (int k = 0; k < 2*NF; k++) {
            float w = Av[k*F + j];
            b1 += agg[64 + 3*k + 1] * w;
            b2 += agg[64 + 3*k + 2] * w;
        }
        ov1[j*3 + 1] = b1 * INV_SQRT_2NF;
        ov1[j*3 + 2] = b2 * INV_SQRT_2NF;
    }
    __syncthreads();
    if (t < F) {
        float a = 0.0f;
        #pragma unroll 8
        for (int k = 0; k < F; k++) a += os1[k] * Bs[k*F + t];
        xs[n*F + t] += a * INV_SQRT_F;
        float b = 0.0f;
        #pragma unroll 8
        for (int k = 0; k < F; k++) b += ov1[k*3 + 0] * Bv[k*F + t];
        xv[n*F*3 + t*3 + 0] += b * INV_SQRT_F;
    } else {
        int j = t - F;
        float b1 = 0.0f, b2 = 0.0f;
        #pragma unroll 8
        for (int k = 0; k < F; k++) {
            float w = Bv[k*F + j];
            b1 += ov1[k*3 + 1] * w;
            b2 += ov1[k*3 + 2] * w;
        }
        xv[n*F*3 + j*3 + 1] += b1 * INV_SQRT_F;
        xv[n*F*3 + j*3 + 2] += b2 * INV_SQRT_F;
    }
}

// ----------------------------------------------------------------
extern "C" void kernel_launch(void* const* d_in, const int* in_sizes, int n_in,
                              void* d_out, int out_size, void* d_ws, size_t ws_size,
                              hipStream_t stream) {
    (void)in_sizes; (void)n_in; (void)out_size; (void)ws_size;
    const int*   Z     = (const int*)  d_in[0];
    const float* r_ij  = (const float*)d_in[1];
    const int*   idx_i = (const int*)  d_in[2];
    const int*   idx_j = (const int*)  d_in[3];
    const float* emb   = (const float*)d_in[4];
    const float* Wpe   = (const float*)d_in[5];
    const float* W0s   = (const float*)d_in[6];
    const float* W0v   = (const float*)d_in[7];
    const float* Wf1   = (const float*)d_in[8];
    const float* bf1   = (const float*)d_in[9];
    const float* Wf2   = (const float*)d_in[10];
    const float* bf2   = (const float*)d_in[11];
    const float* As    = (const float*)d_in[12];
    const float* Av    = (const float*)d_in[13];
    const float* Bs    = (const float*)d_in[14];
    const float* Bv    = (const float*)d_in[15];

    float* xs = (float*)d_out;
    float* ws = (float*)d_ws;
    float* fij  = ws;                    // NE*20
    float* rcut = fij  + (size_t)NE*NRBF;// NE
    float* yv   = rcut + NE;             // NE*3
    float* xv   = yv   + (size_t)NE*3;   // NA*384
    float* hs   = xv   + (size_t)NA*F*3; // NA*32
    float* hv   = hs   + (size_t)NA*NF;  // NA*96
    int*   offs = (int*)(hv + (size_t)NA*NF*3); // NA+1

    hipMemsetAsync(xv, 0, (size_t)NA*F*3*sizeof(float), stream);

    geom_kernel<<<(NE+255)/256, 256, 0, stream>>>(r_ij, fij, rcut, yv);
    offsets_kernel<<<(NA+256)/256, 256, 0, stream>>>(idx_i, offs);
    embed_kernel<<<NA, F, 0, stream>>>(Z, emb, Wpe, xs);

    for (int l = 0; l < 3; l++) {
        h_kernel<<<NA, F, 0, stream>>>(xs, xv,
                                       W0s + (size_t)l*F*NF, W0v + (size_t)l*F*NF,
                                       hs, hv);
        agg_kernel<<<NA, 256, 0, stream>>>(idx_j, offs, fij, rcut, yv, hs, hv,
                                           Wf1 + (size_t)l*NRBF*NF, bf1 + (size_t)l*NF,
                                           Wf2 + (size_t)l*NF*6*NF, bf2 + (size_t)l*6*NF,
                                           As  + (size_t)l*2*NF*F,  Av  + (size_t)l*2*NF*F,
                                           Bs  + (size_t)l*F*F,     Bv  + (size_t)l*F*F,
                                           xs, xv);
    }
}

// Round 4
// 1190.920 us; speedup vs baseline: 1.5374x; 1.0614x over previous
//
#include <hip/hip_runtime.h>
#include <math.h>

constexpr int NA   = 16000;
constexpr int NE   = 256000;
constexpr int F    = 128;
constexpr int NF   = 32;
constexpr int NRBF = 20;
constexpr float CUTOFF       = 5.0f;
constexpr float INV_SQRT_F   = 0.0883883476483184f;  // 1/sqrt(128)
constexpr float INV_SQRT_2NF = 0.125f;               // 1/sqrt(64)
constexpr float INV_SQ3      = 0.5773502691896258f;
constexpr float SQ3          = 1.7320508075688772f;
constexpr float LOG2_        = 0.6931471805599453f;
constexpr float PI_          = 3.14159265358979323f;

__device__ __forceinline__ float ssp(float x) {
    return fmaxf(x, 0.0f) + __logf(1.0f + __expf(-fabsf(x))) - LOG2_;
}

// ---------------------------------------------------------------- K0: per-edge geometry
__global__ void geom_kernel(const float* __restrict__ r_ij,
                            float* __restrict__ fij,
                            float* __restrict__ rcut,
                            float* __restrict__ yv) {
    int e = blockIdx.x * blockDim.x + threadIdx.x;
    if (e >= NE) return;
    float x = r_ij[3*e+0], y = r_ij[3*e+1], z = r_ij[3*e+2];
    float d = sqrtf(x*x + y*y + z*z);
    const float delta = CUTOFF / (NRBF - 1);
    const float coeff = -0.5f / (delta * delta);
    #pragma unroll
    for (int k = 0; k < NRBF; k++) {
        float t = d - delta * (float)k;
        fij[e*NRBF + k] = __expf(coeff * t * t);
    }
    float rc = 0.5f * (__cosf(PI_ * d / CUTOFF) + 1.0f);
    rcut[e] = (d < CUTOFF) ? rc : 0.0f;
    float inv = SQ3 / fmaxf(d, 1e-9f);
    yv[3*e+0] = x * inv;
    yv[3*e+1] = y * inv;
    yv[3*e+2] = z * inv;
}

// ---------------------------------------------------------------- K1: segment offsets (idx_i sorted)
__global__ void offsets_kernel(const int* __restrict__ idx_i, int* __restrict__ offs) {
    int n = blockIdx.x * blockDim.x + threadIdx.x;
    if (n > NA) return;
    int lo = 0, hi = NE;
    while (lo < hi) {
        int mid = (lo + hi) >> 1;
        if (idx_i[mid] < n) lo = mid + 1; else hi = mid;
    }
    offs[n] = lo;
}

// ---------------------------------------------------------------- K2: xs = emb[Z] @ W_pe * inv_sqrt_F
__global__ void embed_kernel(const int* __restrict__ Z,
                             const float* __restrict__ emb,
                             const float* __restrict__ Wpe,
                             float* __restrict__ xs) {
    __shared__ float er[F];
    int n = blockIdx.x, t = threadIdx.x;
    int z = Z[n];
    er[t] = emb[z*F + t];
    __syncthreads();
    float acc = 0.0f;
    #pragma unroll 8
    for (int k = 0; k < F; k++) acc += er[k] * Wpe[k*F + t];
    xs[n*F + t] = acc * INV_SQRT_F;
}

// ---------------------------------------------------------------- K3: hs = xs@W0s*inv, hv = xv@W0v*inv
// xv layout: [n][3][128]  (component-major)
__global__ void h_kernel(const float* __restrict__ xs,
                         const float* __restrict__ xv,
                         const float* __restrict__ W0s,
                         const float* __restrict__ W0v,
                         float* __restrict__ hs,
                         float* __restrict__ hv) {
    __shared__ float sxs[F];
    __shared__ float sxv[F*3];
    int n = blockIdx.x, t = threadIdx.x;   // 128 threads
    sxs[t] = xs[n*F + t];
    sxv[t]       = xv[n*F*3 + t];
    sxv[t + 128] = xv[n*F*3 + t + 128];
    sxv[t + 256] = xv[n*F*3 + t + 256];
    __syncthreads();
    int g = t & 31, sel = t >> 5;
    float acc = 0.0f;
    if (sel == 0) {
        #pragma unroll 8
        for (int k = 0; k < F; k++) acc += sxs[k] * W0s[k*NF + g];
        hs[n*NF + g] = acc * INV_SQRT_F;
    } else {
        int c = sel - 1;
        #pragma unroll 8
        for (int k = 0; k < F; k++) acc += sxv[c*128 + k] * W0v[k*NF + g];
        hv[n*NF*3 + g*3 + c] = acc * INV_SQRT_F;
    }
}

// ---------------------------------------------------------------- K4: wave-per-atom edge aggregation
// One 64-lane wave per atom, private LDS slice, NO __syncthreads (intra-wave
// DS ops are in-order). Each lane accumulates 4 output columns in registers.
// LDS slice layout (floats): SE[32] VE[96] FE[20] YE[4] H1[32] WR[128] -> 320
constexpr int SE = 0, VE = 32, FE = 128, YE = 148, H1 = 152, WR = 184, LW = 320;

__global__ __launch_bounds__(256, 3)
void agg_kernel(const int* __restrict__ idx_j,
                const int* __restrict__ offs,
                const float* __restrict__ fijg,
                const float* __restrict__ rcutg,
                const float* __restrict__ yvg,
                const float* __restrict__ hs,
                const float* __restrict__ hv,
                const float* __restrict__ Wf1,
                const float* __restrict__ bf1,
                const float* __restrict__ Wf2,
                const float* __restrict__ bf2,
                float* __restrict__ aggG) {
    __shared__ float lds[4*LW];
    int wid  = threadIdx.x >> 6;
    int lane = threadIdx.x & 63;
    float* L = lds + wid*LW;
    int n = blockIdx.x*4 + wid;
    int e0 = offs[n], e1 = offs[n+1];

    int g = lane & 31;
    float wf1r[NRBF];
    #pragma unroll
    for (int k = 0; k < NRBF; k++) wf1r[k] = Wf1[k*NF + g];
    float bf1c = bf1[g];
    float wf2a[NF], wf2b[NF];
    #pragma unroll
    for (int k = 0; k < NF; k++) {
        wf2a[k] = Wf2[k*192 + lane];
        wf2b[k] = Wf2[k*192 + 64 + lane];
    }
    float bf2a = bf2[lane], bf2b = bf2[64+lane];

    // column mapping (cols: lane, 64+lane, 128+lane, 192+lane)
    int f1 = lane/3,  c1 = lane - 3*f1;                       // col 64+lane  (t1a)
    int u2 = (lane < 32) ? (64 + lane) : (lane - 32);
    int f2 = u2/3,    c2 = u2 - 3*f2;                         // col 128+lane (t1a tail / t1b head)
    int u3 = lane + 32;
    int f3 = u3/3,    c3 = u3 - 3*f3;                         // col 192+lane (t1b)

    float a0 = 0.f, a1 = 0.f, a2 = 0.f, a3 = 0.f;
    for (int e = e0; e < e1; ++e) {
        int j = idx_j[e];
        // ---- stage edge into wave-private LDS ----
        L[VE + lane] = hv[j*96 + lane];
        if (lane < 32) L[VE + 64 + lane] = hv[j*96 + 64 + lane];
        else           L[SE + lane - 32] = hs[j*32 + lane - 32];
        if (lane < 20)       L[FE + lane]    = fijg[(size_t)e*NRBF + lane];
        else if (lane < 23)  L[YE + lane-20] = yvg[e*3 + lane - 20];
        else if (lane == 23) L[YE + 3]       = rcutg[e];
        // ---- filter MLP layer 1 (lanes 0-31) ----
        if (lane < 32) {
            float a = bf1c;
            #pragma unroll
            for (int k = 0; k < NRBF; k++) a += L[FE+k] * wf1r[k];
            L[H1 + lane] = ssp(a);
        }
        // ---- filter MLP layer 2: 2 cols per lane ----
        {
            float rc = L[YE+3];
            float s0 = bf2a, s1 = bf2b;
            #pragma unroll
            for (int kk = 0; kk < 8; ++kk) {
                float4 h = *(const float4*)&L[H1 + kk*4];
                s0 += h.x*wf2a[4*kk] + h.y*wf2a[4*kk+1] + h.z*wf2a[4*kk+2] + h.w*wf2a[4*kk+3];
                s1 += h.x*wf2b[4*kk] + h.y*wf2b[4*kk+1] + h.z*wf2b[4*kk+2] + h.w*wf2b[4*kk+3];
            }
            L[WR + lane]      = s0 * rc;
            L[WR + 64 + lane] = s1 * rc;
        }
        // ---- accumulate this lane's 4 columns ----
        {
            float y0 = L[YE+0], y1 = L[YE+1], y2 = L[YE+2];
            float v0;
            if (lane < 32) v0 = L[SE+lane] * L[WR+lane];
            else {
                int f = lane - 32;
                v0 = (L[VE+3*f]*y0 + L[VE+3*f+1]*y1 + L[VE+3*f+2]*y2) * INV_SQ3 * L[WR+32+f];
            }
            a0 += v0;
            float yc1 = (c1==0) ? y0 : ((c1==1) ? y1 : y2);
            a1 += L[SE+f1] * yc1 * L[WR+64+f1];
            float yc2 = (c2==0) ? y0 : ((c2==1) ? y1 : y2);
            float v2 = (lane < 32) ? (L[SE+f2] * yc2 * L[WR+64+f2])
                                   : (L[VE+3*f2+c2] * L[WR+96+f2]);
            a2 += v2;
            a3 += L[VE+3*f3+c3] * L[WR+96+f3];
        }
    }
    aggG[(size_t)n*256 + lane]       = a0;
    aggG[(size_t)n*256 + 64 + lane]  = a1;
    aggG[(size_t)n*256 + 128 + lane] = a2;
    aggG[(size_t)n*256 + 192 + lane] = a3;
}

// ---------------------------------------------------------------- K5: batched atom-side MLP
// 16 atoms per 256-thread block. Weights streamed float4 (L1/L2 amortized
// across 16 atoms). Intermediates (os1, ov1) in LDS. xv layout [n][3][128].
__global__ __launch_bounds__(256, 3)
void mlp_kernel(const float* __restrict__ aggG,
                const float* __restrict__ As,
                const float* __restrict__ Av,
                const float* __restrict__ Bs,
                const float* __restrict__ Bv,
                float* __restrict__ xs,
                float* __restrict__ xv) {
    __shared__ float aggL[16][256];
    __shared__ float outL[64][128];   // rows 0-15: os1[atom]; rows 16-63: ov1[(atom,comp)]
    int t = threadIdx.x;
    int a0 = blockIdx.x * 16;
    #pragma unroll
    for (int i = 0; i < 16; i++) aggL[i][t] = aggG[(size_t)(a0+i)*256 + t];
    __syncthreads();

    int q  = t & 31;   // col quad: cols 4q..4q+3
    int rp = t >> 5;   // 0..7
    const float4* As4 = (const float4*)As;
    const float4* Av4 = (const float4*)Av;
    const float4* Bs4 = (const float4*)Bs;
    const float4* Bv4 = (const float4*)Bv;

    // ---- stage 1: os1 = ssp(s_in @ As * inv) ; rows rp, rp+8 ----
    {
        float o0x=0,o0y=0,o0z=0,o0w=0, o1x=0,o1y=0,o1z=0,o1w=0;
        for (int k = 0; k < 64; k++) {
            float4 w = As4[k*32 + q];
            float x0 = aggL[rp][k], x1 = aggL[rp+8][k];
            o0x += x0*w.x; o0y += x0*w.y; o0z += x0*w.z; o0w += x0*w.w;
            o1x += x1*w.x; o1y += x1*w.y; o1z += x1*w.z; o1w += x1*w.w;
        }
        float4 r0 = { ssp(o0x*INV_SQRT_2NF), ssp(o0y*INV_SQRT_2NF), ssp(o0z*INV_SQRT_2NF), ssp(o0w*INV_SQRT_2NF) };
        float4 r1 = { ssp(o1x*INV_SQRT_2NF), ssp(o1y*INV_SQRT_2NF), ssp(o1z*INV_SQRT_2NF), ssp(o1w*INV_SQRT_2NF) };
        *(float4*)&outL[rp][4*q]   = r0;
        *(float4*)&outL[rp+8][4*q] = r1;
    }
    // ---- stage 1: ov1 = v_in @ Av * inv ; 6 rows rv = rp+8i ----
    {
        float o[6][4];
        int ra[6], rc[6];
        #pragma unroll
        for (int i = 0; i < 6; i++) {
            int rv = rp + 8*i;
            ra[i] = rv/3; rc[i] = rv - 3*(rv/3);
            o[i][0]=0; o[i][1]=0; o[i][2]=0; o[i][3]=0;
        }
        for (int k = 0; k < 64; k++) {
            float4 w = Av4[k*32 + q];
            #pragma unroll
            for (int i = 0; i < 6; i++) {
                float x = aggL[ra[i]][64 + 3*k + rc[i]];
                o[i][0] += x*w.x; o[i][1] += x*w.y; o[i][2] += x*w.z; o[i][3] += x*w.w;
            }
        }
        #pragma unroll
        for (int i = 0; i < 6; i++) {
            float4 r = { o[i][0]*INV_SQRT_2NF, o[i][1]*INV_SQRT_2NF, o[i][2]*INV_SQRT_2NF, o[i][3]*INV_SQRT_2NF };
            *(float4*)&outL[16 + rp + 8*i][4*q] = r;
        }
    }
    __syncthreads();
    // ---- stage 2: xs += os1 @ Bs * inv ----
    {
        float o0x=0,o0y=0,o0z=0,o0w=0, o1x=0,o1y=0,o1z=0,o1w=0;
        for (int k = 0; k < 128; k++) {
            float4 w = Bs4[k*32 + q];
            float x0 = outL[rp][k], x1 = outL[rp+8][k];
            o0x += x0*w.x; o0y += x0*w.y; o0z += x0*w.z; o0w += x0*w.w;
            o1x += x1*w.x; o1y += x1*w.y; o1z += x1*w.z; o1w += x1*w.w;
        }
        float4* p0 = (float4*)&xs[(size_t)(a0+rp)*128 + 4*q];
        float4* p1 = (float4*)&xs[(size_t)(a0+rp+8)*128 + 4*q];
        float4 c0 = *p0, c1 = *p1;
        c0.x += o0x*INV_SQRT_F; c0.y += o0y*INV_SQRT_F; c0.z += o0z*INV_SQRT_F; c0.w += o0w*INV_SQRT_F;
        c1.x += o1x*INV_SQRT_F; c1.y += o1y*INV_SQRT_F; c1.z += o1z*INV_SQRT_F; c1.w += o1w*INV_SQRT_F;
        *p0 = c0; *p1 = c1;
    }
    // ---- stage 2: xv += ov1 @ Bv * inv ----
    {
        float o[6][4];
        int ra[6], rc[6];
        #pragma unroll
        for (int i = 0; i < 6; i++) {
            int rv = rp + 8*i;
            ra[i] = rv/3; rc[i] = rv - 3*(rv/3);
            o[i][0]=0; o[i][1]=0; o[i][2]=0; o[i][3]=0;
        }
        for (int k = 0; k < 128; k++) {
            float4 w = Bv4[k*32 + q];
            #pragma unroll
            for (int i = 0; i < 6; i++) {
                float x = outL[16 + rp + 8*i][k];
                o[i][0] += x*w.x; o[i][1] += x*w.y; o[i][2] += x*w.z; o[i][3] += x*w.w;
            }
        }
        #pragma unroll
        for (int i = 0; i < 6; i++) {
            float4* p = (float4*)&xv[(size_t)(a0+ra[i])*384 + rc[i]*128 + 4*q];
            float4 c = *p;
            c.x += o[i][0]*INV_SQRT_F; c.y += o[i][1]*INV_SQRT_F;
            c.z += o[i][2]*INV_SQRT_F; c.w += o[i][3]*INV_SQRT_F;
            *p = c;
        }
    }
}

// ----------------------------------------------------------------
extern "C" void kernel_launch(void* const* d_in, const int* in_sizes, int n_in,
                              void* d_out, int out_size, void* d_ws, size_t ws_size,
                              hipStream_t stream) {
    (void)in_sizes; (void)n_in; (void)out_size; (void)ws_size;
    const int*   Z     = (const int*)  d_in[0];
    const float* r_ij  = (const float*)d_in[1];
    const int*   idx_i = (const int*)  d_in[2];
    const int*   idx_j = (const int*)  d_in[3];
    const float* emb   = (const float*)d_in[4];
    const float* Wpe   = (const float*)d_in[5];
    const float* W0s   = (const float*)d_in[6];
    const float* W0v   = (const float*)d_in[7];
    const float* Wf1   = (const float*)d_in[8];
    const float* bf1   = (const float*)d_in[9];
    const float* Wf2   = (const float*)d_in[10];
    const float* bf2   = (const float*)d_in[11];
    const float* As    = (const float*)d_in[12];
    const float* Av    = (const float*)d_in[13];
    const float* Bs    = (const float*)d_in[14];
    const float* Bv    = (const float*)d_in[15];

    float* xs = (float*)d_out;
    float* ws = (float*)d_ws;
    float* fij  = ws;                     // NE*20
    float* rcut = fij  + (size_t)NE*NRBF; // NE
    float* yv   = rcut + NE;              // NE*3
    float* xv   = yv   + (size_t)NE*3;    // NA*384  ([n][3][128])
    float* hs   = xv   + (size_t)NA*F*3;  // NA*32
    float* hv   = hs   + (size_t)NA*NF;   // NA*96
    float* aggG = hv   + (size_t)NA*NF*3; // NA*256
    int*   offs = (int*)(aggG + (size_t)NA*256); // NA+1

    hipMemsetAsync(xv, 0, (size_t)NA*F*3*sizeof(float), stream);

    geom_kernel<<<(NE+255)/256, 256, 0, stream>>>(r_ij, fij, rcut, yv);
    offsets_kernel<<<(NA+256)/256, 256, 0, stream>>>(idx_i, offs);
    embed_kernel<<<NA, F, 0, stream>>>(Z, emb, Wpe, xs);

    for (int l = 0; l < 3; l++) {
        h_kernel<<<NA, F, 0, stream>>>(xs, xv,
                                       W0s + (size_t)l*F*NF, W0v + (size_t)l*F*NF,
                                       hs, hv);
        agg_kernel<<<NA/4, 256, 0, stream>>>(idx_j, offs, fij, rcut, yv, hs, hv,
                                             Wf1 + (size_t)l*NRBF*NF, bf1 + (size_t)l*NF,
                                             Wf2 + (size_t)l*NF*6*NF, bf2 + (size_t)l*6*NF,
                                             aggG);
        mlp_kernel<<<NA/16, 256, 0, stream>>>(aggG,
                                              As + (size_t)l*2*NF*F, Av + (size_t)l*2*NF*F,
                                              Bs + (size_t)l*F*F,    Bv + (size_t)l*F*F,
                                              xs, xv);
    }
}

// Round 5
// 1158.519 us; speedup vs baseline: 1.5804x; 1.0280x over previous
//
#include <hip/hip_runtime.h>
#include <math.h>

constexpr int NA   = 16000;
constexpr int NE   = 256000;
constexpr int F    = 128;
constexpr int NF   = 32;
constexpr int NRBF = 20;
constexpr float CUTOFF       = 5.0f;
constexpr float INV_SQRT_F   = 0.0883883476483184f;  // 1/sqrt(128)
constexpr float INV_SQRT_2NF = 0.125f;               // 1/sqrt(64)
constexpr float INV_SQ3      = 0.5773502691896258f;
constexpr float SQ3          = 1.7320508075688772f;
constexpr float LOG2_        = 0.6931471805599453f;
constexpr float PI_          = 3.14159265358979323f;

__device__ __forceinline__ float ssp(float x) {
    return fmaxf(x, 0.0f) + __logf(1.0f + __expf(-fabsf(x))) - LOG2_;
}

// ---------------------------------------------------------------- K0: per-edge geometry
// fij packed [e][20] (80B, float4-aligned); yvr packed [e][4] = {yv0,yv1,yv2,rcut}
__global__ void geom_kernel(const float* __restrict__ r_ij,
                            float* __restrict__ fij,
                            float* __restrict__ yvr) {
    int e = blockIdx.x * blockDim.x + threadIdx.x;
    if (e >= NE) return;
    float x = r_ij[3*e+0], y = r_ij[3*e+1], z = r_ij[3*e+2];
    float d = sqrtf(x*x + y*y + z*z);
    const float delta = CUTOFF / (NRBF - 1);
    const float coeff = -0.5f / (delta * delta);
    #pragma unroll
    for (int k = 0; k < NRBF; k++) {
        float t = d - delta * (float)k;
        fij[e*NRBF + k] = __expf(coeff * t * t);
    }
    float rc = 0.5f * (__cosf(PI_ * d / CUTOFF) + 1.0f);
    rc = (d < CUTOFF) ? rc : 0.0f;
    float inv = SQ3 / fmaxf(d, 1e-9f);
    float4 o = { x*inv, y*inv, z*inv, rc };
    *(float4*)&yvr[(size_t)e*4] = o;
}

// ---------------------------------------------------------------- K2: xs = emb[Z] @ W_pe * inv_sqrt_F
__global__ void embed_kernel(const int* __restrict__ Z,
                             const float* __restrict__ emb,
                             const float* __restrict__ Wpe,
                             float* __restrict__ xs) {
    __shared__ float er[F];
    int n = blockIdx.x, t = threadIdx.x;
    int z = Z[n];
    er[t] = emb[z*F + t];
    __syncthreads();
    float acc = 0.0f;
    #pragma unroll 8
    for (int k = 0; k < F; k++) acc += er[k] * Wpe[k*F + t];
    xs[n*F + t] = acc * INV_SQRT_F;
}

// ---------------------------------------------------------------- K3: hs = xs@W0s*inv, hv = xv@W0v*inv
// xv layout: [n][3][128]
__global__ void h_kernel(const float* __restrict__ xs,
                         const float* __restrict__ xv,
                         const float* __restrict__ W0s,
                         const float* __restrict__ W0v,
                         float* __restrict__ hs,
                         float* __restrict__ hv) {
    __shared__ float sxs[F];
    __shared__ float sxv[F*3];
    int n = blockIdx.x, t = threadIdx.x;   // 128 threads
    sxs[t] = xs[n*F + t];
    sxv[t]       = xv[n*F*3 + t];
    sxv[t + 128] = xv[n*F*3 + t + 128];
    sxv[t + 256] = xv[n*F*3 + t + 256];
    __syncthreads();
    int g = t & 31, sel = t >> 5;
    float acc = 0.0f;
    if (sel == 0) {
        #pragma unroll 8
        for (int k = 0; k < F; k++) acc += sxs[k] * W0s[k*NF + g];
        hs[n*NF + g] = acc * INV_SQRT_F;
    } else {
        int c = sel - 1;
        #pragma unroll 8
        for (int k = 0; k < F; k++) acc += sxv[c*128 + k] * W0v[k*NF + g];
        hv[n*NF*3 + g*3 + c] = acc * INV_SQRT_F;
    }
}

// ---------------------------------------------------------------- K4: edge-parallel aggregation
// Wave processes 8-edge chunks (grid-stride). Register accumulation of 4 cols/lane,
// atomic flush at sorted-run boundaries. Wave-private double-buffered LDS slice
// (2 x 160 floats: SJ[0..31], VJ[32..127], H1[128..159]).
__global__ __launch_bounds__(256, 4)
void agg_kernel(const int* __restrict__ idx_i,
                const int* __restrict__ idx_j,
                const float* __restrict__ fijg,
                const float* __restrict__ yvr,
                const float* __restrict__ hs,
                const float* __restrict__ hv,
                const float* __restrict__ Wf1,
                const float* __restrict__ bf1,
                const float* __restrict__ Wf2,
                const float* __restrict__ bf2,
                float* __restrict__ aggG) {
    __shared__ float LWf1[NRBF*NF];   // 640 floats
    __shared__ float lds[4*320];
    int t = threadIdx.x;
    for (int u = t; u < NRBF*NF; u += 256) LWf1[u] = Wf1[u];
    __syncthreads();

    int wid = t >> 6, lane = t & 63;
    float* Lb = lds + wid*320;
    int g = lane & 31;
    float bf1c = bf1[g];
    float wf2a[NF], wf2b[NF];
    #pragma unroll
    for (int k = 0; k < NF; k++) {
        wf2a[k] = Wf2[k*192 + lane];
        wf2b[k] = Wf2[k*192 + 64 + lane];
    }
    float bf2a = bf2[lane], bf2b = bf2[64 + lane];

    // static per-lane column mapping (cols: lane, 64+lane, 128+lane, 192+lane)
    int f1 = lane/3, c1 = lane - 3*f1;                    // col 64+lane (t1a)
    int u2 = (lane < 32) ? (64 + lane) : (lane - 32);
    int f2 = u2/3, c2 = u2 - 3*f2;                        // col 128+lane
    int src2 = (lane < 32) ? f2 : (32 + f2);
    int f3 = (32 + lane)/3;                               // col 192+lane (t1b)
    int src3 = 32 + f3;

    int wg = blockIdx.x*4 + wid;                          // 4096 waves total
    for (int ch = wg; ch < NE/8; ch += 4096) {
        int base = ch*8;
        int4 ja = *(const int4*)(idx_j + base);
        int4 jb = *(const int4*)(idx_j + base + 4);
        int jv[8] = { ja.x, ja.y, ja.z, ja.w, jb.x, jb.y, jb.z, jb.w };
        float a0 = 0.f, a1 = 0.f, a2 = 0.f, a3 = 0.f;
        int prev = idx_i[base];
        #pragma unroll
        for (int i = 0; i < 8; i++) {
            int e = base + i;
            int j = jv[i];
            int ni = (i == 0) ? prev : idx_i[e];
            float* B = Lb + (i & 1)*160;
            // gathers (coalesced within the j rows)
            float vjA = hv[j*96 + lane];                                  // vj[0..63]
            const float* sp = (lane < 32) ? (hs + j*32 + lane)            // sj[lane]
                                          : (hv + j*96 + 32 + lane);      // vj[32+lane]
            float sv = *sp;
            const float4* fp = (const float4*)(fijg + (size_t)e*20);
            float4 q0 = fp[0], q1 = fp[1], q2 = fp[2], q3 = fp[3], q4 = fp[4];
            float4 yr = *(const float4*)(yvr + (size_t)e*4);
            // run-boundary flush (wave-uniform branch)
            if (ni != prev) {
                unsafeAtomicAdd(&aggG[(size_t)prev*256 + lane],       a0);
                unsafeAtomicAdd(&aggG[(size_t)prev*256 + 64 + lane],  a1);
                unsafeAtomicAdd(&aggG[(size_t)prev*256 + 128 + lane], a2);
                unsafeAtomicAdd(&aggG[(size_t)prev*256 + 192 + lane], a3);
                a0 = a1 = a2 = a3 = 0.f;
                prev = ni;
            }
            // stage into wave-private buffer
            B[32 + lane] = vjA;
            B[(lane < 32) ? lane : (64 + lane)] = sv;
            // MLP1 (both halves redundantly compute h1[g])
            float h = bf1c;
            h += q0.x*LWf1[0*32+g]  + q0.y*LWf1[1*32+g]  + q0.z*LWf1[2*32+g]  + q0.w*LWf1[3*32+g];
            h += q1.x*LWf1[4*32+g]  + q1.y*LWf1[5*32+g]  + q1.z*LWf1[6*32+g]  + q1.w*LWf1[7*32+g];
            h += q2.x*LWf1[8*32+g]  + q2.y*LWf1[9*32+g]  + q2.z*LWf1[10*32+g] + q2.w*LWf1[11*32+g];
            h += q3.x*LWf1[12*32+g] + q3.y*LWf1[13*32+g] + q3.z*LWf1[14*32+g] + q3.w*LWf1[15*32+g];
            h += q4.x*LWf1[16*32+g] + q4.y*LWf1[17*32+g] + q4.z*LWf1[18*32+g] + q4.w*LWf1[19*32+g];
            h = ssp(h);
            if (lane < 32) B[128 + g] = h;
            // MLP2: lane's two W columns (lane, 64+lane) from reg weights
            float s0 = bf2a, s1 = bf2b;
            #pragma unroll
            for (int kk = 0; kk < 8; kk++) {
                float4 hq = *(const float4*)&B[128 + kk*4];
                s0 += hq.x*wf2a[4*kk] + hq.y*wf2a[4*kk+1] + hq.z*wf2a[4*kk+2] + hq.w*wf2a[4*kk+3];
                s1 += hq.x*wf2b[4*kk] + hq.y*wf2b[4*kk+1] + hq.z*wf2b[4*kk+2] + hq.w*wf2b[4*kk+3];
            }
            float w0 = s0 * yr.w, w1 = s1 * yr.w;
            float w1f1 = __shfl(w1, f1);
            float w1f2 = __shfl(w1, src2);
            float w1f3 = __shfl(w1, src3);
            // accumulate 4 owned columns
            float v0;
            if (lane < 32) v0 = sv * w0;
            else {
                int f = lane - 32;
                v0 = (B[32+3*f]*yr.x + B[32+3*f+1]*yr.y + B[32+3*f+2]*yr.z) * INV_SQ3 * w0;
            }
            float yc1 = (c1 == 0) ? yr.x : ((c1 == 1) ? yr.y : yr.z);
            float t1v = B[f1] * yc1 * w1f1;
            float op2;
            if (lane < 32) {
                float yc2 = (c2 == 0) ? yr.x : ((c2 == 1) ? yr.y : yr.z);
                op2 = B[f2] * yc2;
            } else {
                op2 = B[lane];            // vj[lane-32]
            }
            float t2v = op2 * w1f2;
            float op3 = (lane < 32) ? B[64 + lane] : sv;   // vj[32+lane]
            float t3v = op3 * w1f3;
            a0 += v0; a1 += t1v; a2 += t2v; a3 += t3v;
        }
        unsafeAtomicAdd(&aggG[(size_t)prev*256 + lane],       a0);
        unsafeAtomicAdd(&aggG[(size_t)prev*256 + 64 + lane],  a1);
        unsafeAtomicAdd(&aggG[(size_t)prev*256 + 128 + lane], a2);
        unsafeAtomicAdd(&aggG[(size_t)prev*256 + 192 + lane], a3);
    }
}

// ---------------------------------------------------------------- K5: batched atom-side MLP
__global__ __launch_bounds__(256, 3)
void mlp_kernel(const float* __restrict__ aggG,
                const float* __restrict__ As,
                const float* __restrict__ Av,
                const float* __restrict__ Bs,
                const float* __restrict__ Bv,
                float* __restrict__ xs,
                float* __restrict__ xv) {
    __shared__ float aggL[16][256];
    __shared__ float outL[64][128];
    int t = threadIdx.x;
    int a0 = blockIdx.x * 16;
    #pragma unroll
    for (int i = 0; i < 16; i++) aggL[i][t] = aggG[(size_t)(a0+i)*256 + t];
    __syncthreads();

    int q  = t & 31;
    int rp = t >> 5;
    const float4* As4 = (const float4*)As;
    const float4* Av4 = (const float4*)Av;
    const float4* Bs4 = (const float4*)Bs;
    const float4* Bv4 = (const float4*)Bv;

    {
        float o0x=0,o0y=0,o0z=0,o0w=0, o1x=0,o1y=0,o1z=0,o1w=0;
        for (int k = 0; k < 64; k++) {
            float4 w = As4[k*32 + q];
            float x0 = aggL[rp][k], x1 = aggL[rp+8][k];
            o0x += x0*w.x; o0y += x0*w.y; o0z += x0*w.z; o0w += x0*w.w;
            o1x += x1*w.x; o1y += x1*w.y; o1z += x1*w.z; o1w += x1*w.w;
        }
        float4 r0 = { ssp(o0x*INV_SQRT_2NF), ssp(o0y*INV_SQRT_2NF), ssp(o0z*INV_SQRT_2NF), ssp(o0w*INV_SQRT_2NF) };
        float4 r1 = { ssp(o1x*INV_SQRT_2NF), ssp(o1y*INV_SQRT_2NF), ssp(o1z*INV_SQRT_2NF), ssp(o1w*INV_SQRT_2NF) };
        *(float4*)&outL[rp][4*q]   = r0;
        *(float4*)&outL[rp+8][4*q] = r1;
    }
    {
        float o[6][4];
        int ra[6], rc[6];
        #pragma unroll
        for (int i = 0; i < 6; i++) {
            int rv = rp + 8*i;
            ra[i] = rv/3; rc[i] = rv - 3*(rv/3);
            o[i][0]=0; o[i][1]=0; o[i][2]=0; o[i][3]=0;
        }
        for (int k = 0; k < 64; k++) {
            float4 w = Av4[k*32 + q];
            #pragma unroll
            for (int i = 0; i < 6; i++) {
                float x = aggL[ra[i]][64 + 3*k + rc[i]];
                o[i][0] += x*w.x; o[i][1] += x*w.y; o[i][2] += x*w.z; o[i][3] += x*w.w;
            }
        }
        #pragma unroll
        for (int i = 0; i < 6; i++) {
            float4 r = { o[i][0]*INV_SQRT_2NF, o[i][1]*INV_SQRT_2NF, o[i][2]*INV_SQRT_2NF, o[i][3]*INV_SQRT_2NF };
            *(float4*)&outL[16 + rp + 8*i][4*q] = r;
        }
    }
    __syncthreads();
    {
        float o0x=0,o0y=0,o0z=0,o0w=0, o1x=0,o1y=0,o1z=0,o1w=0;
        for (int k = 0; k < 128; k++) {
            float4 w = Bs4[k*32 + q];
            float x0 = outL[rp][k], x1 = outL[rp+8][k];
            o0x += x0*w.x; o0y += x0*w.y; o0z += x0*w.z; o0w += x0*w.w;
            o1x += x1*w.x; o1y += x1*w.y; o1z += x1*w.z; o1w += x1*w.w;
        }
        float4* p0 = (float4*)&xs[(size_t)(a0+rp)*128 + 4*q];
        float4* p1 = (float4*)&xs[(size_t)(a0+rp+8)*128 + 4*q];
        float4 c0 = *p0, c1 = *p1;
        c0.x += o0x*INV_SQRT_F; c0.y += o0y*INV_SQRT_F; c0.z += o0z*INV_SQRT_F; c0.w += o0w*INV_SQRT_F;
        c1.x += o1x*INV_SQRT_F; c1.y += o1y*INV_SQRT_F; c1.z += o1z*INV_SQRT_F; c1.w += o1w*INV_SQRT_F;
        *p0 = c0; *p1 = c1;
    }
    {
        float o[6][4];
        int ra[6], rc[6];
        #pragma unroll
        for (int i = 0; i < 6; i++) {
            int rv = rp + 8*i;
            ra[i] = rv/3; rc[i] = rv - 3*(rv/3);
            o[i][0]=0; o[i][1]=0; o[i][2]=0; o[i][3]=0;
        }
        for (int k = 0; k < 128; k++) {
            float4 w = Bv4[k*32 + q];
            #pragma unroll
            for (int i = 0; i < 6; i++) {
                float x = outL[16 + rp + 8*i][k];
                o[i][0] += x*w.x; o[i][1] += x*w.y; o[i][2] += x*w.z; o[i][3] += x*w.w;
            }
        }
        #pragma unroll
        for (int i = 0; i < 6; i++) {
            float4* p = (float4*)&xv[(size_t)(a0+ra[i])*384 + rc[i]*128 + 4*q];
            float4 c = *p;
            c.x += o[i][0]*INV_SQRT_F; c.y += o[i][1]*INV_SQRT_F;
            c.z += o[i][2]*INV_SQRT_F; c.w += o[i][3]*INV_SQRT_F;
            *p = c;
        }
    }
}

// ----------------------------------------------------------------
extern "C" void kernel_launch(void* const* d_in, const int* in_sizes, int n_in,
                              void* d_out, int out_size, void* d_ws, size_t ws_size,
                              hipStream_t stream) {
    (void)in_sizes; (void)n_in; (void)out_size; (void)ws_size;
    const int*   Z     = (const int*)  d_in[0];
    const float* r_ij  = (const float*)d_in[1];
    const int*   idx_i = (const int*)  d_in[2];
    const int*   idx_j = (const int*)  d_in[3];
    const float* emb   = (const float*)d_in[4];
    const float* Wpe   = (const float*)d_in[5];
    const float* W0s   = (const float*)d_in[6];
    const float* W0v   = (const float*)d_in[7];
    const float* Wf1   = (const float*)d_in[8];
    const float* bf1   = (const float*)d_in[9];
    const float* Wf2   = (const float*)d_in[10];
    const float* bf2   = (const float*)d_in[11];
    const float* As    = (const float*)d_in[12];
    const float* Av    = (const float*)d_in[13];
    const float* Bs    = (const float*)d_in[14];
    const float* Bv    = (const float*)d_in[15];

    float* xs = (float*)d_out;
    float* ws = (float*)d_ws;
    float* fij  = ws;                     // NE*20
    float* yvr  = fij  + (size_t)NE*NRBF; // NE*4
    float* xv   = yvr  + (size_t)NE*4;    // NA*384  ([n][3][128])
    float* hs   = xv   + (size_t)NA*F*3;  // NA*32
    float* hv   = hs   + (size_t)NA*NF;   // NA*96
    float* aggG = hv   + (size_t)NA*NF*3; // NA*256

    hipMemsetAsync(xv, 0, (size_t)NA*F*3*sizeof(float), stream);

    geom_kernel<<<(NE+255)/256, 256, 0, stream>>>(r_ij, fij, yvr);
    embed_kernel<<<NA, F, 0, stream>>>(Z, emb, Wpe, xs);

    for (int l = 0; l < 3; l++) {
        h_kernel<<<NA, F, 0, stream>>>(xs, xv,
                                       W0s + (size_t)l*F*NF, W0v + (size_t)l*F*NF,
                                       hs, hv);
        hipMemsetAsync(aggG, 0, (size_t)NA*256*sizeof(float), stream);
        agg_kernel<<<1024, 256, 0, stream>>>(idx_i, idx_j, fij, yvr, hs, hv,
                                             Wf1 + (size_t)l*NRBF*NF, bf1 + (size_t)l*NF,
                                             Wf2 + (size_t)l*NF*6*NF, bf2 + (size_t)l*6*NF,
                                             aggG);
        mlp_kernel<<<NA/16, 256, 0, stream>>>(aggG,
                                              As + (size_t)l*2*NF*F, Av + (size_t)l*2*NF*F,
                                              Bs + (size_t)l*F*F,    Bv + (size_t)l*F*F,
                                              xs, xv);
    }
}

// Round 6
// 1056.721 us; speedup vs baseline: 1.7326x; 1.0963x over previous
//
#include <hip/hip_runtime.h>
#include <math.h>

constexpr int NA   = 16000;
constexpr int NE   = 256000;
constexpr int F    = 128;
constexpr int NF   = 32;
constexpr int NRBF = 20;
constexpr float CUTOFF       = 5.0f;
constexpr float INV_SQRT_F   = 0.0883883476483184f;  // 1/sqrt(128)
constexpr float INV_SQRT_2NF = 0.125f;               // 1/sqrt(64)
constexpr float INV_SQ3      = 0.5773502691896258f;
constexpr float SQ3          = 1.7320508075688772f;
constexpr float LOG2_        = 0.6931471805599453f;
constexpr float PI_          = 3.14159265358979323f;

__device__ __forceinline__ float ssp(float x) {
    return fmaxf(x, 0.0f) + __logf(1.0f + __expf(-fabsf(x))) - LOG2_;
}

// ---------------------------------------------------------------- K0: per-edge geometry
__global__ void geom_kernel(const float* __restrict__ r_ij,
                            float* __restrict__ fij,
                            float* __restrict__ yvr) {
    int e = blockIdx.x * blockDim.x + threadIdx.x;
    if (e >= NE) return;
    float x = r_ij[3*e+0], y = r_ij[3*e+1], z = r_ij[3*e+2];
    float d = sqrtf(x*x + y*y + z*z);
    const float delta = CUTOFF / (NRBF - 1);
    const float coeff = -0.5f / (delta * delta);
    #pragma unroll
    for (int k = 0; k < NRBF; k++) {
        float t = d - delta * (float)k;
        fij[e*NRBF + k] = __expf(coeff * t * t);
    }
    float rc = 0.5f * (__cosf(PI_ * d / CUTOFF) + 1.0f);
    rc = (d < CUTOFF) ? rc : 0.0f;
    float inv = SQ3 / fmaxf(d, 1e-9f);
    float4 o = { x*inv, y*inv, z*inv, rc };
    *(float4*)&yvr[(size_t)e*4] = o;
}

// ---------------------------------------------------------------- K2: xs = emb[Z] @ W_pe (32 atoms/block)
__global__ __launch_bounds__(256, 4)
void embed_kernel(const int* __restrict__ Z,
                  const float* __restrict__ emb,
                  const float* __restrict__ Wpe,
                  float* __restrict__ xs) {
    __shared__ float ER[32][128];     // 16KB
    __shared__ int   Zs[32];
    int t = threadIdx.x;
    int a0 = blockIdx.x * 32;
    if (t < 32) Zs[t] = Z[a0 + t];
    __syncthreads();
    {
        const float4* emb4 = (const float4*)emb;
        float4* ER4 = (float4*)&ER[0][0];
        #pragma unroll
        for (int it = 0; it < 4; it++) {
            int u4 = it*256 + t;                  // 0..1023
            int a = u4 >> 5, k4 = u4 & 31;
            ER4[u4] = emb4[(size_t)Zs[a]*32 + k4];
        }
    }
    __syncthreads();
    int c = t & 127, half = t >> 7;
    float acc[16];
    #pragma unroll
    for (int a = 0; a < 16; a++) acc[a] = 0.f;
    for (int k = 0; k < 128; k++) {
        float w = Wpe[k*128 + c];
        #pragma unroll
        for (int a = 0; a < 16; a++) acc[a] += ER[half*16 + a][k] * w;
    }
    #pragma unroll
    for (int a = 0; a < 16; a++)
        xs[(size_t)(a0 + half*16 + a)*128 + c] = acc[a] * INV_SQRT_F;
}

// ---------------------------------------------------------------- K3: hs/hv projection (16 atoms/block)
// xv layout [n][3][128]; hs[n][32]; hv[n*96 + g*3 + c]
__global__ __launch_bounds__(256, 4)
void h_kernel(const float* __restrict__ xs,
              const float* __restrict__ xv,
              const float* __restrict__ W0s,
              const float* __restrict__ W0v,
              float* __restrict__ hs,
              float* __restrict__ hv) {
    __shared__ float X[16][512];      // 32KB: [atom][xs 0..127 | xv 128..511]
    int t = threadIdx.x;
    int a0 = blockIdx.x * 16;
    {
        float* Xf = &X[0][0];
        const float4* xs4 = (const float4*)xs;
        const float4* xv4 = (const float4*)xv;
        #pragma unroll
        for (int it = 0; it < 2; it++) {          // xs: 512 float4
            int u4 = it*256 + t;
            int a = u4 >> 5, k4 = u4 & 31;
            *(float4*)&Xf[a*512 + k4*4] = xs4[(size_t)a0*32 + u4];
        }
        #pragma unroll
        for (int it = 0; it < 6; it++) {          // xv: 1536 float4
            int u4 = it*256 + t;
            int a = u4 / 96, rem = u4 - a*96;
            *(float4*)&Xf[a*512 + 128 + rem*4] = xv4[(size_t)a0*96 + u4];
        }
    }
    __syncthreads();
    int g = t & 31, r = t >> 5;        // r: 0..7
    int sel = r & 3, half = r >> 2;    // sel 0: hs; 1..3: hv comp
    const float* W = (sel == 0) ? W0s : W0v;
    int xoff = (sel == 0) ? 0 : (128 + (sel-1)*128);
    float acc[8];
    #pragma unroll
    for (int a = 0; a < 8; a++) acc[a] = 0.f;
    for (int k = 0; k < 128; k++) {
        float w = W[k*32 + g];
        #pragma unroll
        for (int a = 0; a < 8; a++) acc[a] += X[half*8 + a][xoff + k] * w;
    }
    #pragma unroll
    for (int a = 0; a < 8; a++) {
        int n = a0 + half*8 + a;
        if (sel == 0) hs[(size_t)n*32 + g] = acc[a] * INV_SQRT_F;
        else          hv[(size_t)n*96 + g*3 + (sel-1)] = acc[a] * INV_SQRT_F;
    }
}

// ---------------------------------------------------------------- K4: edge-parallel aggregation
// 2000 blocks (8000 waves, 4 chunks each). Wave-private dbuf LDS slice.
__global__ __launch_bounds__(256, 4)
void agg_kernel(const int* __restrict__ idx_i,
                const int* __restrict__ idx_j,
                const float* __restrict__ fijg,
                const float* __restrict__ yvr,
                const float* __restrict__ hs,
                const float* __restrict__ hv,
                const float* __restrict__ Wf1,
                const float* __restrict__ bf1,
                const float* __restrict__ Wf2,
                const float* __restrict__ bf2,
                float* __restrict__ aggG) {
    __shared__ float LWf1[NRBF*NF];   // 640 floats
    __shared__ float lds[4*320];
    int t = threadIdx.x;
    for (int u = t; u < NRBF*NF; u += 256) LWf1[u] = Wf1[u];
    __syncthreads();

    int wid = t >> 6, lane = t & 63;
    float* Lb = lds + wid*320;
    int g = lane & 31;
    float bf1c = bf1[g];
    float wf2a[NF], wf2b[NF];
    #pragma unroll
    for (int k = 0; k < NF; k++) {
        wf2a[k] = Wf2[k*192 + lane];
        wf2b[k] = Wf2[k*192 + 64 + lane];
    }
    float bf2a = bf2[lane], bf2b = bf2[64 + lane];

    int f1 = lane/3, c1 = lane - 3*f1;
    int u2 = (lane < 32) ? (64 + lane) : (lane - 32);
    int f2 = u2/3, c2 = u2 - 3*f2;
    int src2 = (lane < 32) ? f2 : (32 + f2);
    int f3 = (32 + lane)/3;
    int src3 = 32 + f3;

    int wg = blockIdx.x*4 + wid;                  // 8000 waves
    for (int ch = wg; ch < NE/8; ch += 8000) {
        int base = ch*8;
        int4 ja = *(const int4*)(idx_j + base);
        int4 jb = *(const int4*)(idx_j + base + 4);
        int jv[8] = { ja.x, ja.y, ja.z, ja.w, jb.x, jb.y, jb.z, jb.w };
        float a0 = 0.f, a1 = 0.f, a2 = 0.f, a3 = 0.f;
        int prev = idx_i[base];
        #pragma unroll
        for (int i = 0; i < 8; i++) {
            int e = base + i;
            int j = jv[i];
            int ni = (i == 0) ? prev : idx_i[e];
            float* B = Lb + (i & 1)*160;
            float vjA = hv[j*96 + lane];
            const float* sp = (lane < 32) ? (hs + j*32 + lane)
                                          : (hv + j*96 + 32 + lane);
            float sv = *sp;
            const float4* fp = (const float4*)(fijg + (size_t)e*20);
            float4 q0 = fp[0], q1 = fp[1], q2 = fp[2], q3 = fp[3], q4 = fp[4];
            float4 yr = *(const float4*)(yvr + (size_t)e*4);
            if (ni != prev) {
                unsafeAtomicAdd(&aggG[(size_t)prev*256 + lane],       a0);
                unsafeAtomicAdd(&aggG[(size_t)prev*256 + 64 + lane],  a1);
                unsafeAtomicAdd(&aggG[(size_t)prev*256 + 128 + lane], a2);
                unsafeAtomicAdd(&aggG[(size_t)prev*256 + 192 + lane], a3);
                a0 = a1 = a2 = a3 = 0.f;
                prev = ni;
            }
            B[32 + lane] = vjA;
            B[(lane < 32) ? lane : (64 + lane)] = sv;
            float h = bf1c;
            h += q0.x*LWf1[0*32+g]  + q0.y*LWf1[1*32+g]  + q0.z*LWf1[2*32+g]  + q0.w*LWf1[3*32+g];
            h += q1.x*LWf1[4*32+g]  + q1.y*LWf1[5*32+g]  + q1.z*LWf1[6*32+g]  + q1.w*LWf1[7*32+g];
            h += q2.x*LWf1[8*32+g]  + q2.y*LWf1[9*32+g]  + q2.z*LWf1[10*32+g] + q2.w*LWf1[11*32+g];
            h += q3.x*LWf1[12*32+g] + q3.y*LWf1[13*32+g] + q3.z*LWf1[14*32+g] + q3.w*LWf1[15*32+g];
            h += q4.x*LWf1[16*32+g] + q4.y*LWf1[17*32+g] + q4.z*LWf1[18*32+g] + q4.w*LWf1[19*32+g];
            h = ssp(h);
            if (lane < 32) B[128 + g] = h;
            float s0 = bf2a, s1 = bf2b;
            #pragma unroll
            for (int kk = 0; kk < 8; kk++) {
                float4 hq = *(const float4*)&B[128 + kk*4];
                s0 += hq.x*wf2a[4*kk] + hq.y*wf2a[4*kk+1] + hq.z*wf2a[4*kk+2] + hq.w*wf2a[4*kk+3];
                s1 += hq.x*wf2b[4*kk] + hq.y*wf2b[4*kk+1] + hq.z*wf2b[4*kk+2] + hq.w*wf2b[4*kk+3];
            }
            float w0 = s0 * yr.w, w1 = s1 * yr.w;
            float w1f1 = __shfl(w1, f1);
            float w1f2 = __shfl(w1, src2);
            float w1f3 = __shfl(w1, src3);
            float v0;
            if (lane < 32) v0 = sv * w0;
            else {
                int f = lane - 32;
                v0 = (B[32+3*f]*yr.x + B[32+3*f+1]*yr.y + B[32+3*f+2]*yr.z) * INV_SQ3 * w0;
            }
            float yc1 = (c1 == 0) ? yr.x : ((c1 == 1) ? yr.y : yr.z);
            float t1v = B[f1] * yc1 * w1f1;
            float op2;
            if (lane < 32) {
                float yc2 = (c2 == 0) ? yr.x : ((c2 == 1) ? yr.y : yr.z);
                op2 = B[f2] * yc2;
            } else {
                op2 = B[lane];
            }
            float t2v = op2 * w1f2;
            float op3 = (lane < 32) ? B[64 + lane] : sv;
            float t3v = op3 * w1f3;
            a0 += v0; a1 += t1v; a2 += t2v; a3 += t3v;
        }
        unsafeAtomicAdd(&aggG[(size_t)prev*256 + lane],       a0);
        unsafeAtomicAdd(&aggG[(size_t)prev*256 + 64 + lane],  a1);
        unsafeAtomicAdd(&aggG[(size_t)prev*256 + 128 + lane], a2);
        unsafeAtomicAdd(&aggG[(size_t)prev*256 + 192 + lane], a3);
    }
}

// ---------------------------------------------------------------- K5: batched atom-side MLP
__global__ __launch_bounds__(256, 3)
void mlp_kernel(const float* __restrict__ aggG,
                const float* __restrict__ As,
                const float* __restrict__ Av,
                const float* __restrict__ Bs,
                const float* __restrict__ Bv,
                float* __restrict__ xs,
                float* __restrict__ xv) {
    __shared__ float aggL[16][256];
    __shared__ float outL[64][128];
    int t = threadIdx.x;
    int a0 = blockIdx.x * 16;
    #pragma unroll
    for (int i = 0; i < 16; i++) aggL[i][t] = aggG[(size_t)(a0+i)*256 + t];
    __syncthreads();

    int q  = t & 31;
    int rp = t >> 5;
    const float4* As4 = (const float4*)As;
    const float4* Av4 = (const float4*)Av;
    const float4* Bs4 = (const float4*)Bs;
    const float4* Bv4 = (const float4*)Bv;

    {
        float o0x=0,o0y=0,o0z=0,o0w=0, o1x=0,o1y=0,o1z=0,o1w=0;
        for (int k = 0; k < 64; k++) {
            float4 w = As4[k*32 + q];
            float x0 = aggL[rp][k], x1 = aggL[rp+8][k];
            o0x += x0*w.x; o0y += x0*w.y; o0z += x0*w.z; o0w += x0*w.w;
            o1x += x1*w.x; o1y += x1*w.y; o1z += x1*w.z; o1w += x1*w.w;
        }
        float4 r0 = { ssp(o0x*INV_SQRT_2NF), ssp(o0y*INV_SQRT_2NF), ssp(o0z*INV_SQRT_2NF), ssp(o0w*INV_SQRT_2NF) };
        float4 r1 = { ssp(o1x*INV_SQRT_2NF), ssp(o1y*INV_SQRT_2NF), ssp(o1z*INV_SQRT_2NF), ssp(o1w*INV_SQRT_2NF) };
        *(float4*)&outL[rp][4*q]   = r0;
        *(float4*)&outL[rp+8][4*q] = r1;
    }
    {
        float o[6][4];
        int ra[6], rc[6];
        #pragma unroll
        for (int i = 0; i < 6; i++) {
            int rv = rp + 8*i;
            ra[i] = rv/3; rc[i] = rv - 3*(rv/3);
            o[i][0]=0; o[i][1]=0; o[i][2]=0; o[i][3]=0;
        }
        for (int k = 0; k < 64; k++) {
            float4 w = Av4[k*32 + q];
            #pragma unroll
            for (int i = 0; i < 6; i++) {
                float x = aggL[ra[i]][64 + 3*k + rc[i]];
                o[i][0] += x*w.x; o[i][1] += x*w.y; o[i][2] += x*w.z; o[i][3] += x*w.w;
            }
        }
        #pragma unroll
        for (int i = 0; i < 6; i++) {
            float4 r = { o[i][0]*INV_SQRT_2NF, o[i][1]*INV_SQRT_2NF, o[i][2]*INV_SQRT_2NF, o[i][3]*INV_SQRT_2NF };
            *(float4*)&outL[16 + rp + 8*i][4*q] = r;
        }
    }
    __syncthreads();
    {
        float o0x=0,o0y=0,o0z=0,o0w=0, o1x=0,o1y=0,o1z=0,o1w=0;
        for (int k = 0; k < 128; k++) {
            float4 w = Bs4[k*32 + q];
            float x0 = outL[rp][k], x1 = outL[rp+8][k];
            o0x += x0*w.x; o0y += x0*w.y; o0z += x0*w.z; o0w += x0*w.w;
            o1x += x1*w.x; o1y += x1*w.y; o1z += x1*w.z; o1w += x1*w.w;
        }
        float4* p0 = (float4*)&xs[(size_t)(a0+rp)*128 + 4*q];
        float4* p1 = (float4*)&xs[(size_t)(a0+rp+8)*128 + 4*q];
        float4 c0 = *p0, c1 = *p1;
        c0.x += o0x*INV_SQRT_F; c0.y += o0y*INV_SQRT_F; c0.z += o0z*INV_SQRT_F; c0.w += o0w*INV_SQRT_F;
        c1.x += o1x*INV_SQRT_F; c1.y += o1y*INV_SQRT_F; c1.z += o1z*INV_SQRT_F; c1.w += o1w*INV_SQRT_F;
        *p0 = c0; *p1 = c1;
    }
    {
        float o[6][4];
        int ra[6], rc[6];
        #pragma unroll
        for (int i = 0; i < 6; i++) {
            int rv = rp + 8*i;
            ra[i] = rv/3; rc[i] = rv - 3*(rv/3);
            o[i][0]=0; o[i][1]=0; o[i][2]=0; o[i][3]=0;
        }
        for (int k = 0; k < 128; k++) {
            float4 w = Bv4[k*32 + q];
            #pragma unroll
            for (int i = 0; i < 6; i++) {
                float x = outL[16 + rp + 8*i][k];
                o[i][0] += x*w.x; o[i][1] += x*w.y; o[i][2] += x*w.z; o[i][3] += x*w.w;
            }
        }
        #pragma unroll
        for (int i = 0; i < 6; i++) {
            float4* p = (float4*)&xv[(size_t)(a0+ra[i])*384 + rc[i]*128 + 4*q];
            float4 c = *p;
            c.x += o[i][0]*INV_SQRT_F; c.y += o[i][1]*INV_SQRT_F;
            c.z += o[i][2]*INV_SQRT_F; c.w += o[i][3]*INV_SQRT_F;
            *p = c;
        }
    }
}

// ----------------------------------------------------------------
extern "C" void kernel_launch(void* const* d_in, const int* in_sizes, int n_in,
                              void* d_out, int out_size, void* d_ws, size_t ws_size,
                              hipStream_t stream) {
    (void)in_sizes; (void)n_in; (void)out_size; (void)ws_size;
    const int*   Z     = (const int*)  d_in[0];
    const float* r_ij  = (const float*)d_in[1];
    const int*   idx_i = (const int*)  d_in[2];
    const int*   idx_j = (const int*)  d_in[3];
    const float* emb   = (const float*)d_in[4];
    const float* Wpe   = (const float*)d_in[5];
    const float* W0s   = (const float*)d_in[6];
    const float* W0v   = (const float*)d_in[7];
    const float* Wf1   = (const float*)d_in[8];
    const float* bf1   = (const float*)d_in[9];
    const float* Wf2   = (const float*)d_in[10];
    const float* bf2   = (const float*)d_in[11];
    const float* As    = (const float*)d_in[12];
    const float* Av    = (const float*)d_in[13];
    const float* Bs    = (const float*)d_in[14];
    const float* Bv    = (const float*)d_in[15];

    float* xs = (float*)d_out;
    float* ws = (float*)d_ws;
    float* fij  = ws;                     // NE*20
    float* yvr  = fij  + (size_t)NE*NRBF; // NE*4
    float* xv   = yvr  + (size_t)NE*4;    // NA*384  ([n][3][128])
    float* hs   = xv   + (size_t)NA*F*3;  // NA*32
    float* hv   = hs   + (size_t)NA*NF;   // NA*96
    float* aggG = hv   + (size_t)NA*NF*3; // NA*256

    hipMemsetAsync(xv, 0, (size_t)NA*F*3*sizeof(float), stream);

    geom_kernel<<<(NE+255)/256, 256, 0, stream>>>(r_ij, fij, yvr);
    embed_kernel<<<NA/32, 256, 0, stream>>>(Z, emb, Wpe, xs);

    for (int l = 0; l < 3; l++) {
        h_kernel<<<NA/16, 256, 0, stream>>>(xs, xv,
                                            W0s + (size_t)l*F*NF, W0v + (size_t)l*F*NF,
                                            hs, hv);
        hipMemsetAsync(aggG, 0, (size_t)NA*256*sizeof(float), stream);
        agg_kernel<<<2000, 256, 0, stream>>>(idx_i, idx_j, fij, yvr, hs, hv,
                                             Wf1 + (size_t)l*NRBF*NF, bf1 + (size_t)l*NF,
                                             Wf2 + (size_t)l*NF*6*NF, bf2 + (size_t)l*6*NF,
                                             aggG);
        mlp_kernel<<<NA/16, 256, 0, stream>>>(aggG,
                                              As + (size_t)l*2*NF*F, Av + (size_t)l*2*NF*F,
                                              Bs + (size_t)l*F*F,    Bv + (size_t)l*F*F,
                                              xs, xv);
    }
}

// Round 7
// 558.548 us; speedup vs baseline: 3.2780x; 1.8919x over previous
//
#include <hip/hip_runtime.h>
#include <math.h>

constexpr int NA   = 16000;
constexpr int NE   = 256000;
constexpr int F    = 128;
constexpr int NF   = 32;
constexpr int NRBF = 20;
constexpr float CUTOFF       = 5.0f;
constexpr float INV_SQRT_F   = 0.0883883476483184f;  // 1/sqrt(128)
constexpr float INV_SQRT_2NF = 0.125f;               // 1/sqrt(64)
constexpr float INV_SQ3      = 0.5773502691896258f;
constexpr float SQ3          = 1.7320508075688772f;
constexpr float LOG2_        = 0.6931471805599453f;
constexpr float PI_          = 3.14159265358979323f;

__device__ __forceinline__ float ssp(float x) {
    return fmaxf(x, 0.0f) + __logf(1.0f + __expf(-fabsf(x))) - LOG2_;
}
__device__ __forceinline__ float rlane_f(float v, int l) {
    return __int_as_float(__builtin_amdgcn_readlane(__float_as_int(v), l));
}

// ---------------------------------------------------------------- K0: per-edge geometry (transposed outputs)
// fijT[k][e], yvrT[c][e] (c=0..2: Yv, c=3: rcut) — all stores coalesced
__global__ void geom_kernel(const float* __restrict__ r_ij,
                            float* __restrict__ fijT,
                            float* __restrict__ yvrT) {
    int e = blockIdx.x * blockDim.x + threadIdx.x;
    if (e >= NE) return;
    float x = r_ij[3*e+0], y = r_ij[3*e+1], z = r_ij[3*e+2];
    float d = sqrtf(x*x + y*y + z*z);
    const float delta = CUTOFF / (NRBF - 1);
    const float coeff = -0.5f / (delta * delta);
    #pragma unroll
    for (int k = 0; k < NRBF; k++) {
        float t = d - delta * (float)k;
        fijT[(size_t)k*NE + e] = __expf(coeff * t * t);
    }
    float rc = 0.5f * (__cosf(PI_ * d / CUTOFF) + 1.0f);
    rc = (d < CUTOFF) ? rc : 0.0f;
    float inv = SQ3 / fmaxf(d, 1e-9f);
    yvrT[0*(size_t)NE + e] = x * inv;
    yvrT[1*(size_t)NE + e] = y * inv;
    yvrT[2*(size_t)NE + e] = z * inv;
    yvrT[3*(size_t)NE + e] = rc;
}

// ---------------------------------------------------------------- prep: Wf2T[l][c][k] = Wf2[l][k][c], c<128
__global__ void prep_kernel(const float* __restrict__ Wf2, float* __restrict__ Wf2T) {
    int u = blockIdx.x * 256 + threadIdx.x;
    if (u >= 3*128*32) return;
    int l = u >> 12, rem = u & 4095, c = rem >> 5, k = rem & 31;
    Wf2T[u] = Wf2[(size_t)l*NF*192 + k*192 + c];
}

// ---------------------------------------------------------------- K2: xs = emb[Z] @ W_pe (32 atoms/block)
__global__ __launch_bounds__(256, 4)
void embed_kernel(const int* __restrict__ Z,
                  const float* __restrict__ emb,
                  const float* __restrict__ Wpe,
                  float* __restrict__ xs) {
    __shared__ float ER[32][128];
    __shared__ int   Zs[32];
    int t = threadIdx.x;
    int a0 = blockIdx.x * 32;
    if (t < 32) Zs[t] = Z[a0 + t];
    __syncthreads();
    {
        const float4* emb4 = (const float4*)emb;
        float4* ER4 = (float4*)&ER[0][0];
        #pragma unroll
        for (int it = 0; it < 4; it++) {
            int u4 = it*256 + t;
            int a = u4 >> 5, k4 = u4 & 31;
            ER4[u4] = emb4[(size_t)Zs[a]*32 + k4];
        }
    }
    __syncthreads();
    int c = t & 127, half = t >> 7;
    float acc[16];
    #pragma unroll
    for (int a = 0; a < 16; a++) acc[a] = 0.f;
    for (int k = 0; k < 128; k++) {
        float w = Wpe[k*128 + c];
        #pragma unroll
        for (int a = 0; a < 16; a++) acc[a] += ER[half*16 + a][k] * w;
    }
    #pragma unroll
    for (int a = 0; a < 16; a++)
        xs[(size_t)(a0 + half*16 + a)*128 + c] = acc[a] * INV_SQRT_F;
}

// ---------------------------------------------------------------- K3: hsv projection (16 atoms/block)
// hsv[n][128]: [0..31] = hs, [32 + g*3 + c] = hv ; xv layout [n][3][128]
__global__ __launch_bounds__(256, 4)
void h_kernel(const float* __restrict__ xs,
              const float* __restrict__ xv,
              const float* __restrict__ W0s,
              const float* __restrict__ W0v,
              float* __restrict__ hsv) {
    __shared__ float X[16][512];
    int t = threadIdx.x;
    int a0 = blockIdx.x * 16;
    {
        float* Xf = &X[0][0];
        const float4* xs4 = (const float4*)xs;
        const float4* xv4 = (const float4*)xv;
        #pragma unroll
        for (int it = 0; it < 2; it++) {
            int u4 = it*256 + t;
            int a = u4 >> 5, k4 = u4 & 31;
            *(float4*)&Xf[a*512 + k4*4] = xs4[(size_t)a0*32 + u4];
        }
        #pragma unroll
        for (int it = 0; it < 6; it++) {
            int u4 = it*256 + t;
            int a = u4 / 96, rem = u4 - a*96;
            *(float4*)&Xf[a*512 + 128 + rem*4] = xv4[(size_t)a0*96 + u4];
        }
    }
    __syncthreads();
    int g = t & 31, r = t >> 5;
    int sel = r & 3, half = r >> 2;
    const float* W = (sel == 0) ? W0s : W0v;
    int xoff = (sel == 0) ? 0 : (128 + (sel-1)*128);
    float acc[8];
    #pragma unroll
    for (int a = 0; a < 8; a++) acc[a] = 0.f;
    for (int k = 0; k < 128; k++) {
        float w = W[k*32 + g];
        #pragma unroll
        for (int a = 0; a < 8; a++) acc[a] += X[half*8 + a][xoff + k] * w;
    }
    #pragma unroll
    for (int a = 0; a < 8; a++) {
        int n = a0 + half*8 + a;
        if (sel == 0) hsv[(size_t)n*128 + g] = acc[a] * INV_SQRT_F;
        else          hsv[(size_t)n*128 + 32 + g*3 + (sel-1)] = acc[a] * INV_SQRT_F;
    }
}

// ---------------------------------------------------------------- K4: edge aggregation, 64 edges/wave
// Lane-per-edge MLP1; per-edge scalars via v_readlane (SGPR); product operands
// via direct L1 gathers from hsv row (j in SGPR); h1 round-trip via wave-private LDS.
__global__ __launch_bounds__(256, 4)
void agg_kernel(const int* __restrict__ idx_i,
                const int* __restrict__ idx_j,
                const float* __restrict__ fijT,
                const float* __restrict__ yvrT,
                const float* __restrict__ hsv,
                const float* __restrict__ Wf1,
                const float* __restrict__ bf1,
                const float* __restrict__ Wf2T,
                const float* __restrict__ bf2,
                float* __restrict__ aggG) {
    __shared__ float LWf1[NRBF*NF];     // 2560 B
    __shared__ float HB[4][64][36];     // 36864 B, wave-private h1 tiles
    int t = threadIdx.x;
    for (int u = t; u < NRBF*NF; u += 256) LWf1[u] = Wf1[u];
    __syncthreads();

    int wid = t >> 6, lane = t & 63;
    int base = (blockIdx.x*4 + wid) * 64;

    // ---- prologue: coalesced per-edge data (lane -> edge base+lane) ----
    int   il = idx_i[base + lane];
    int   jl = idx_j[base + lane];
    float y0l = yvrT[0*(size_t)NE + base + lane];
    float y1l = yvrT[1*(size_t)NE + base + lane];
    float y2l = yvrT[2*(size_t)NE + base + lane];
    float y3l = yvrT[3*(size_t)NE + base + lane];

    // ---- MLP1, lane-per-edge ----
    float h[32];
    #pragma unroll
    for (int g = 0; g < 32; g++) h[g] = bf1[g];
    #pragma unroll
    for (int k = 0; k < NRBF; k++) {
        float fk = fijT[(size_t)k*NE + base + lane];
        #pragma unroll
        for (int q = 0; q < 8; q++) {
            float4 w = *(const float4*)&LWf1[k*32 + q*4];
            h[q*4+0] += fk * w.x;
            h[q*4+1] += fk * w.y;
            h[q*4+2] += fk * w.z;
            h[q*4+3] += fk * w.w;
        }
    }
    #pragma unroll
    for (int g = 0; g < 32; g++) h[g] = ssp(h[g]);
    #pragma unroll
    for (int q = 0; q < 8; q++) {
        float4 v = { h[q*4], h[q*4+1], h[q*4+2], h[q*4+3] };
        *(float4*)&HB[wid][lane][q*4] = v;
    }

    // ---- per-lane weights (2 Wr columns: lane, 64+lane) ----
    float4 w2a[8], w2b[8];
    #pragma unroll
    for (int q = 0; q < 8; q++) {
        w2a[q] = *(const float4*)&Wf2T[lane*32 + q*4];
        w2b[q] = *(const float4*)&Wf2T[(64+lane)*32 + q*4];
    }
    float bf2a = bf2[lane], bf2b = bf2[64 + lane];

    // ---- static per-lane column mapping ----
    int f1 = lane/3, c1 = lane - 3*f1;
    int u2 = (lane < 32) ? (64 + lane) : (lane - 32);
    int f2 = u2/3, c2 = u2 - 3*f2;
    int src2 = (lane < 32) ? f2 : (32 + f2);
    int f3 = (32 + lane)/3;
    int src3 = 32 + f3;
    int idxQ0 = (lane < 32) ? lane : (32 + 3*(lane-32));
    int idxQ1 = (lane < 32) ? lane : (idxQ0 + 1);
    int idxQ2 = (lane < 32) ? lane : (idxQ0 + 2);
    int idxA2 = (lane < 32) ? f2 : lane;
    int idxA3 = 64 + lane;

    float a0 = 0.f, a1 = 0.f, a2 = 0.f, a3 = 0.f;
    int prev = __builtin_amdgcn_readlane(il, 0);
    const float* hb = &HB[wid][0][0];

    for (int ii = 0; ii < 64; ++ii) {
        int eix = __builtin_amdgcn_readlane(il, ii);
        if (eix != prev) {
            unsafeAtomicAdd(&aggG[(size_t)prev*256 + lane],       a0);
            unsafeAtomicAdd(&aggG[(size_t)prev*256 + 64 + lane],  a1);
            unsafeAtomicAdd(&aggG[(size_t)prev*256 + 128 + lane], a2);
            unsafeAtomicAdd(&aggG[(size_t)prev*256 + 192 + lane], a3);
            a0 = a1 = a2 = a3 = 0.f;
            prev = eix;
        }
        int j = __builtin_amdgcn_readlane(jl, ii);
        const float* row = hsv + (size_t)j*128;
        float q0  = row[idxQ0];
        float q1  = row[idxQ1];
        float q2  = row[idxQ2];
        float sf1 = row[f1];
        float oA2 = row[idxA2];
        float oA3 = row[idxA3];
        // MLP2 for edge ii (h1 broadcast from LDS)
        float s0 = bf2a, s1 = bf2b;
        const float* hrow = hb + ii*36;
        #pragma unroll
        for (int q = 0; q < 8; q++) {
            float4 hq = *(const float4*)&hrow[q*4];
            s0 += hq.x*w2a[q].x + hq.y*w2a[q].y + hq.z*w2a[q].z + hq.w*w2a[q].w;
            s1 += hq.x*w2b[q].x + hq.y*w2b[q].y + hq.z*w2b[q].z + hq.w*w2b[q].w;
        }
        float y3s = rlane_f(y3l, ii);
        float w0 = s0 * y3s, w1 = s1 * y3s;
        float w1f1 = __shfl(w1, f1);
        float w1f2 = __shfl(w1, src2);
        float w1f3 = __shfl(w1, src3);
        float y0s = rlane_f(y0l, ii);
        float y1s = rlane_f(y1l, ii);
        float y2s = rlane_f(y2l, ii);
        float vv = (q0*y0s + q1*y1s + q2*y2s) * INV_SQ3;
        float v0 = (lane < 32) ? q0 : vv;
        a0 += v0 * w0;
        float yc1 = (c1 == 0) ? y0s : ((c1 == 1) ? y1s : y2s);
        a1 += sf1 * yc1 * w1f1;
        float yc2 = (c2 == 0) ? y0s : ((c2 == 1) ? y1s : y2s);
        float m2 = (lane < 32) ? yc2 : 1.0f;
        a2 += oA2 * m2 * w1f2;
        a3 += oA3 * w1f3;
    }
    unsafeAtomicAdd(&aggG[(size_t)prev*256 + lane],       a0);
    unsafeAtomicAdd(&aggG[(size_t)prev*256 + 64 + lane],  a1);
    unsafeAtomicAdd(&aggG[(size_t)prev*256 + 128 + lane], a2);
    unsafeAtomicAdd(&aggG[(size_t)prev*256 + 192 + lane], a3);
}

// ---------------------------------------------------------------- K5: batched atom-side MLP
__global__ __launch_bounds__(256, 3)
void mlp_kernel(const float* __restrict__ aggG,
                const float* __restrict__ As,
                const float* __restrict__ Av,
                const float* __restrict__ Bs,
                const float* __restrict__ Bv,
                float* __restrict__ xs,
                float* __restrict__ xv) {
    __shared__ float aggL[16][256];
    __shared__ float outL[64][128];
    int t = threadIdx.x;
    int a0 = blockIdx.x * 16;
    #pragma unroll
    for (int i = 0; i < 16; i++) aggL[i][t] = aggG[(size_t)(a0+i)*256 + t];
    __syncthreads();

    int q  = t & 31;
    int rp = t >> 5;
    const float4* As4 = (const float4*)As;
    const float4* Av4 = (const float4*)Av;
    const float4* Bs4 = (const float4*)Bs;
    const float4* Bv4 = (const float4*)Bv;

    {
        float o0x=0,o0y=0,o0z=0,o0w=0, o1x=0,o1y=0,o1z=0,o1w=0;
        for (int k = 0; k < 64; k++) {
            float4 w = As4[k*32 + q];
            float x0 = aggL[rp][k], x1 = aggL[rp+8][k];
            o0x += x0*w.x; o0y += x0*w.y; o0z += x0*w.z; o0w += x0*w.w;
            o1x += x1*w.x; o1y += x1*w.y; o1z += x1*w.z; o1w += x1*w.w;
        }
        float4 r0 = { ssp(o0x*INV_SQRT_2NF), ssp(o0y*INV_SQRT_2NF), ssp(o0z*INV_SQRT_2NF), ssp(o0w*INV_SQRT_2NF) };
        float4 r1 = { ssp(o1x*INV_SQRT_2NF), ssp(o1y*INV_SQRT_2NF), ssp(o1z*INV_SQRT_2NF), ssp(o1w*INV_SQRT_2NF) };
        *(float4*)&outL[rp][4*q]   = r0;
        *(float4*)&outL[rp+8][4*q] = r1;
    }
    {
        float o[6][4];
        int ra[6], rc[6];
        #pragma unroll
        for (int i = 0; i < 6; i++) {
            int rv = rp + 8*i;
            ra[i] = rv/3; rc[i] = rv - 3*(rv/3);
            o[i][0]=0; o[i][1]=0; o[i][2]=0; o[i][3]=0;
        }
        for (int k = 0; k < 64; k++) {
            float4 w = Av4[k*32 + q];
            #pragma unroll
            for (int i = 0; i < 6; i++) {
                float x = aggL[ra[i]][64 + 3*k + rc[i]];
                o[i][0] += x*w.x; o[i][1] += x*w.y; o[i][2] += x*w.z; o[i][3] += x*w.w;
            }
        }
        #pragma unroll
        for (int i = 0; i < 6; i++) {
            float4 r = { o[i][0]*INV_SQRT_2NF, o[i][1]*INV_SQRT_2NF, o[i][2]*INV_SQRT_2NF, o[i][3]*INV_SQRT_2NF };
            *(float4*)&outL[16 + rp + 8*i][4*q] = r;
        }
    }
    __syncthreads();
    {
        float o0x=0,o0y=0,o0z=0,o0w=0, o1x=0,o1y=0,o1z=0,o1w=0;
        for (int k = 0; k < 128; k++) {
            float4 w = Bs4[k*32 + q];
            float x0 = outL[rp][k], x1 = outL[rp+8][k];
            o0x += x0*w.x; o0y += x0*w.y; o0z += x0*w.z; o0w += x0*w.w;
            o1x += x1*w.x; o1y += x1*w.y; o1z += x1*w.z; o1w += x1*w.w;
        }
        float4* p0 = (float4*)&xs[(size_t)(a0+rp)*128 + 4*q];
        float4* p1 = (float4*)&xs[(size_t)(a0+rp+8)*128 + 4*q];
        float4 c0 = *p0, c1 = *p1;
        c0.x += o0x*INV_SQRT_F; c0.y += o0y*INV_SQRT_F; c0.z += o0z*INV_SQRT_F; c0.w += o0w*INV_SQRT_F;
        c1.x += o1x*INV_SQRT_F; c1.y += o1y*INV_SQRT_F; c1.z += o1z*INV_SQRT_F; c1.w += o1w*INV_SQRT_F;
        *p0 = c0; *p1 = c1;
    }
    {
        float o[6][4];
        int ra[6], rc[6];
        #pragma unroll
        for (int i = 0; i < 6; i++) {
            int rv = rp + 8*i;
            ra[i] = rv/3; rc[i] = rv - 3*(rv/3);
            o[i][0]=0; o[i][1]=0; o[i][2]=0; o[i][3]=0;
        }
        for (int k = 0; k < 128; k++) {
            float4 w = Bv4[k*32 + q];
            #pragma unroll
            for (int i = 0; i < 6; i++) {
                float x = outL[16 + rp + 8*i][k];
                o[i][0] += x*w.x; o[i][1] += x*w.y; o[i][2] += x*w.z; o[i][3] += x*w.w;
            }
        }
        #pragma unroll
        for (int i = 0; i < 6; i++) {
            float4* p = (float4*)&xv[(size_t)(a0+ra[i])*384 + rc[i]*128 + 4*q];
            float4 c = *p;
            c.x += o[i][0]*INV_SQRT_F; c.y += o[i][1]*INV_SQRT_F;
            c.z += o[i][2]*INV_SQRT_F; c.w += o[i][3]*INV_SQRT_F;
            *p = c;
        }
    }
}

// ----------------------------------------------------------------
extern "C" void kernel_launch(void* const* d_in, const int* in_sizes, int n_in,
                              void* d_out, int out_size, void* d_ws, size_t ws_size,
                              hipStream_t stream) {
    (void)in_sizes; (void)n_in; (void)out_size; (void)ws_size;
    const int*   Z     = (const int*)  d_in[0];
    const float* r_ij  = (const float*)d_in[1];
    const int*   idx_i = (const int*)  d_in[2];
    const int*   idx_j = (const int*)  d_in[3];
    const float* emb   = (const float*)d_in[4];
    const float* Wpe   = (const float*)d_in[5];
    const float* W0s   = (const float*)d_in[6];
    const float* W0v   = (const float*)d_in[7];
    const float* Wf1   = (const float*)d_in[8];
    const float* bf1   = (const float*)d_in[9];
    const float* Wf2   = (const float*)d_in[10];
    const float* bf2   = (const float*)d_in[11];
    const float* As    = (const float*)d_in[12];
    const float* Av    = (const float*)d_in[13];
    const float* Bs    = (const float*)d_in[14];
    const float* Bv    = (const float*)d_in[15];

    float* xs = (float*)d_out;
    float* ws = (float*)d_ws;
    float* fijT = ws;                      // NE*20
    float* yvrT = fijT + (size_t)NE*NRBF;  // NE*4
    float* xv   = yvrT + (size_t)NE*4;     // NA*384  ([n][3][128])
    float* hsv  = xv   + (size_t)NA*F*3;   // NA*128
    float* aggG = hsv  + (size_t)NA*F;     // NA*256
    float* Wf2T = aggG + (size_t)NA*256;   // 3*128*32

    hipMemsetAsync(xv, 0, (size_t)NA*F*3*sizeof(float), stream);

    geom_kernel<<<(NE+255)/256, 256, 0, stream>>>(r_ij, fijT, yvrT);
    prep_kernel<<<(3*128*32+255)/256, 256, 0, stream>>>(Wf2, Wf2T);
    embed_kernel<<<NA/32, 256, 0, stream>>>(Z, emb, Wpe, xs);

    for (int l = 0; l < 3; l++) {
        h_kernel<<<NA/16, 256, 0, stream>>>(xs, xv,
                                            W0s + (size_t)l*F*NF, W0v + (size_t)l*F*NF,
                                            hsv);
        hipMemsetAsync(aggG, 0, (size_t)NA*256*sizeof(float), stream);
        agg_kernel<<<NE/256, 256, 0, stream>>>(idx_i, idx_j, fijT, yvrT, hsv,
                                               Wf1 + (size_t)l*NRBF*NF, bf1 + (size_t)l*NF,
                                               Wf2T + (size_t)l*128*32, bf2 + (size_t)l*6*NF,
                                               aggG);
        mlp_kernel<<<NA/16, 256, 0, stream>>>(aggG,
                                              As + (size_t)l*2*NF*F, Av + (size_t)l*2*NF*F,
                                              Bs + (size_t)l*F*F,    Bv + (size_t)l*F*F,
                                              xs, xv);
    }
}

// Round 8
// 530.306 us; speedup vs baseline: 3.4526x; 1.0533x over previous
//
#include <hip/hip_runtime.h>
#include <math.h>

constexpr int NA   = 16000;
constexpr int NE   = 256000;
constexpr int F    = 128;
constexpr int NF   = 32;
constexpr int NRBF = 20;
constexpr float CUTOFF       = 5.0f;
constexpr float INV_SQRT_F   = 0.0883883476483184f;  // 1/sqrt(128)
constexpr float INV_SQRT_2NF = 0.125f;               // 1/sqrt(64)
constexpr float INV_SQ3      = 0.5773502691896258f;
constexpr float SQ3          = 1.7320508075688772f;
constexpr float LOG2_        = 0.6931471805599453f;
constexpr float PI_          = 3.14159265358979323f;

__device__ __forceinline__ float ssp(float x) {
    return fmaxf(x, 0.0f) + __logf(1.0f + __expf(-fabsf(x))) - LOG2_;
}
__device__ __forceinline__ float rlane_f(float v, int l) {
    return __int_as_float(__builtin_amdgcn_readlane(__float_as_int(v), l));
}

// ---------------------------------------------------------------- K0: per-edge geometry (transposed outputs)
__global__ void geom_kernel(const float* __restrict__ r_ij,
                            float* __restrict__ fijT,
                            float* __restrict__ yvrT) {
    int e = blockIdx.x * blockDim.x + threadIdx.x;
    if (e >= NE) return;
    float x = r_ij[3*e+0], y = r_ij[3*e+1], z = r_ij[3*e+2];
    float d = sqrtf(x*x + y*y + z*z);
    const float delta = CUTOFF / (NRBF - 1);
    const float coeff = -0.5f / (delta * delta);
    #pragma unroll
    for (int k = 0; k < NRBF; k++) {
        float t = d - delta * (float)k;
        fijT[(size_t)k*NE + e] = __expf(coeff * t * t);
    }
    float rc = 0.5f * (__cosf(PI_ * d / CUTOFF) + 1.0f);
    rc = (d < CUTOFF) ? rc : 0.0f;
    float inv = SQ3 / fmaxf(d, 1e-9f);
    yvrT[0*(size_t)NE + e] = x * inv;
    yvrT[1*(size_t)NE + e] = y * inv;
    yvrT[2*(size_t)NE + e] = z * inv;
    yvrT[3*(size_t)NE + e] = rc;
}

// ---------------------------------------------------------------- prep: Wf2T[l][c][k] = Wf2[l][k][c], c<128
__global__ void prep_kernel(const float* __restrict__ Wf2, float* __restrict__ Wf2T) {
    int u = blockIdx.x * 256 + threadIdx.x;
    if (u >= 3*128*32) return;
    int l = u >> 12, rem = u & 4095, c = rem >> 5, k = rem & 31;
    Wf2T[u] = Wf2[(size_t)l*NF*192 + k*192 + c];
}

// ---------------------------------------------------------------- K2: xs = emb[Z] @ W_pe (32 atoms/block)
__global__ __launch_bounds__(256, 4)
void embed_kernel(const int* __restrict__ Z,
                  const float* __restrict__ emb,
                  const float* __restrict__ Wpe,
                  float* __restrict__ xs) {
    __shared__ float ER[32][128];
    __shared__ int   Zs[32];
    int t = threadIdx.x;
    int a0 = blockIdx.x * 32;
    if (t < 32) Zs[t] = Z[a0 + t];
    __syncthreads();
    {
        const float4* emb4 = (const float4*)emb;
        float4* ER4 = (float4*)&ER[0][0];
        #pragma unroll
        for (int it = 0; it < 4; it++) {
            int u4 = it*256 + t;
            int a = u4 >> 5, k4 = u4 & 31;
            ER4[u4] = emb4[(size_t)Zs[a]*32 + k4];
        }
    }
    __syncthreads();
    int c = t & 127, half = t >> 7;
    float acc[16];
    #pragma unroll
    for (int a = 0; a < 16; a++) acc[a] = 0.f;
    for (int k = 0; k < 128; k++) {
        float w = Wpe[k*128 + c];
        #pragma unroll
        for (int a = 0; a < 16; a++) acc[a] += ER[half*16 + a][k] * w;
    }
    #pragma unroll
    for (int a = 0; a < 16; a++)
        xs[(size_t)(a0 + half*16 + a)*128 + c] = acc[a] * INV_SQRT_F;
}

// ---------------------------------------------------------------- K3: hsv projection (16 atoms/block)
// hsv[n][128]: [0..31] = hs, [32 + g*3 + c] = hv ; xv layout [n][3][128]
__global__ __launch_bounds__(256, 4)
void h_kernel(const float* __restrict__ xs,
              const float* __restrict__ xv,
              const float* __restrict__ W0s,
              const float* __restrict__ W0v,
              float* __restrict__ hsv) {
    __shared__ float X[16][512];
    int t = threadIdx.x;
    int a0 = blockIdx.x * 16;
    {
        float* Xf = &X[0][0];
        const float4* xs4 = (const float4*)xs;
        const float4* xv4 = (const float4*)xv;
        #pragma unroll
        for (int it = 0; it < 2; it++) {
            int u4 = it*256 + t;
            int a = u4 >> 5, k4 = u4 & 31;
            *(float4*)&Xf[a*512 + k4*4] = xs4[(size_t)a0*32 + u4];
        }
        #pragma unroll
        for (int it = 0; it < 6; it++) {
            int u4 = it*256 + t;
            int a = u4 / 96, rem = u4 - a*96;
            *(float4*)&Xf[a*512 + 128 + rem*4] = xv4[(size_t)a0*96 + u4];
        }
    }
    __syncthreads();
    int g = t & 31, r = t >> 5;
    int sel = r & 3, half = r >> 2;
    const float* W = (sel == 0) ? W0s : W0v;
    int xoff = (sel == 0) ? 0 : (128 + (sel-1)*128);
    float acc[8];
    #pragma unroll
    for (int a = 0; a < 8; a++) acc[a] = 0.f;
    for (int k = 0; k < 128; k++) {
        float w = W[k*32 + g];
        #pragma unroll
        for (int a = 0; a < 8; a++) acc[a] += X[half*8 + a][xoff + k] * w;
    }
    #pragma unroll
    for (int a = 0; a < 8; a++) {
        int n = a0 + half*8 + a;
        if (sel == 0) hsv[(size_t)n*128 + g] = acc[a] * INV_SQRT_F;
        else          hsv[(size_t)n*128 + 32 + g*3 + (sel-1)] = acc[a] * INV_SQRT_F;
    }
}

// ---------------------------------------------------------------- K4: edge aggregation, 64 edges/wave
// aggG layout per atom row (256): [0..63] s-cols; [64 + c*64 + f] = v_in[f][c].
// Each lane's 4 columns need only its OWN Wr values (no shuffles).
__global__ __launch_bounds__(256, 4)
void agg_kernel(const int* __restrict__ idx_i,
                const int* __restrict__ idx_j,
                const float* __restrict__ fijT,
                const float* __restrict__ yvrT,
                const float* __restrict__ hsv,
                const float* __restrict__ Wf1,
                const float* __restrict__ bf1,
                const float* __restrict__ Wf2T,
                const float* __restrict__ bf2,
                float* __restrict__ aggG) {
    __shared__ float LWf1[NRBF*NF];     // 2560 B
    __shared__ float HB[4][64][36];     // 36864 B
    int t = threadIdx.x;
    for (int u = t; u < NRBF*NF; u += 256) LWf1[u] = Wf1[u];
    __syncthreads();

    int wid = t >> 6, lane = t & 63;
    int base = (blockIdx.x*4 + wid) * 64;

    // ---- coalesced per-edge data (lane -> edge base+lane) ----
    int   il = idx_i[base + lane];
    int   jl = idx_j[base + lane];
    float y0l = yvrT[0*(size_t)NE + base + lane];
    float y1l = yvrT[1*(size_t)NE + base + lane];
    float y2l = yvrT[2*(size_t)NE + base + lane];
    float y3l = yvrT[3*(size_t)NE + base + lane];

    // run-boundary mask (one ballot per chunk)
    int ilp = __shfl_up(il, 1);
    unsigned long long bmask = __ballot(lane > 0 && il != ilp);

    // ---- MLP1, lane-per-edge ----
    float h[32];
    #pragma unroll
    for (int g = 0; g < 32; g++) h[g] = bf1[g];
    #pragma unroll
    for (int k = 0; k < NRBF; k++) {
        float fk = fijT[(size_t)k*NE + base + lane];
        #pragma unroll
        for (int q = 0; q < 8; q++) {
            float4 w = *(const float4*)&LWf1[k*32 + q*4];
            h[q*4+0] += fk * w.x;
            h[q*4+1] += fk * w.y;
            h[q*4+2] += fk * w.z;
            h[q*4+3] += fk * w.w;
        }
    }
    #pragma unroll
    for (int g = 0; g < 32; g++) h[g] = ssp(h[g]);
    #pragma unroll
    for (int q = 0; q < 8; q++) {
        float4 v = { h[q*4], h[q*4+1], h[q*4+2], h[q*4+3] };
        *(float4*)&HB[wid][lane][q*4] = v;
    }

    // ---- per-lane weights (own 2 Wr columns: lane, 64+lane) ----
    float4 w2a[8], w2b[8];
    #pragma unroll
    for (int q = 0; q < 8; q++) {
        w2a[q] = *(const float4*)&Wf2T[lane*32 + q*4];
        w2b[q] = *(const float4*)&Wf2T[(64+lane)*32 + q*4];
    }
    float bf2a = bf2[lane], bf2b = bf2[64 + lane];

    int idxQ = 32 + 3*(lane - 32);     // vj triple base (lane>=32)

    float a0 = 0.f, a1 = 0.f, a2 = 0.f, a3 = 0.f;
    int prev = __builtin_amdgcn_readlane(il, 0);
    const float* hb = &HB[wid][0][0];

    for (int ii = 0; ii < 64; ++ii) {
        if ((bmask >> ii) & 1ull) {
            unsafeAtomicAdd(&aggG[(size_t)prev*256 + lane],       a0);
            unsafeAtomicAdd(&aggG[(size_t)prev*256 + 64 + lane],  a1);
            unsafeAtomicAdd(&aggG[(size_t)prev*256 + 128 + lane], a2);
            unsafeAtomicAdd(&aggG[(size_t)prev*256 + 192 + lane], a3);
            a0 = a1 = a2 = a3 = 0.f;
            prev = __builtin_amdgcn_readlane(il, ii);
        }
        int j = __builtin_amdgcn_readlane(jl, ii);
        const float* row = hsv + (size_t)j*128;
        float q0, q1, q2;
        if (lane < 32) {
            q0 = row[lane]; q1 = q0; q2 = q0;
        } else {
            const float* p = row + idxQ;
            q0 = p[0]; q1 = p[1]; q2 = p[2];
        }
        // MLP2: own two columns
        float s0 = bf2a, s1 = bf2b;
        const float* hrow = hb + ii*36;
        #pragma unroll
        for (int qq = 0; qq < 8; qq++) {
            float4 hq = *(const float4*)&hrow[qq*4];
            s0 += hq.x*w2a[qq].x + hq.y*w2a[qq].y + hq.z*w2a[qq].z + hq.w*w2a[qq].w;
            s1 += hq.x*w2b[qq].x + hq.y*w2b[qq].y + hq.z*w2b[qq].z + hq.w*w2b[qq].w;
        }
        float y3s = rlane_f(y3l, ii);
        float y0s = rlane_f(y0l, ii);
        float y1s = rlane_f(y1l, ii);
        float y2s = rlane_f(y2l, ii);
        float w0 = s0 * y3s, w1 = s1 * y3s;
        float dot = (q0*y0s + q1*y1s + q2*y2s) * INV_SQ3;
        float v0 = (lane < 32) ? q0 : dot;
        float m1 = (lane < 32) ? y0s : 1.0f;
        float m2 = (lane < 32) ? y1s : 1.0f;
        float m3 = (lane < 32) ? y2s : 1.0f;
        a0 += v0 * w0;
        a1 += q0 * m1 * w1;
        a2 += q1 * m2 * w1;
        a3 += q2 * m3 * w1;
    }
    unsafeAtomicAdd(&aggG[(size_t)prev*256 + lane],       a0);
    unsafeAtomicAdd(&aggG[(size_t)prev*256 + 64 + lane],  a1);
    unsafeAtomicAdd(&aggG[(size_t)prev*256 + 128 + lane], a2);
    unsafeAtomicAdd(&aggG[(size_t)prev*256 + 192 + lane], a3);
}

// ---------------------------------------------------------------- K5: batched atom-side MLP (b128 LDS reads)
// aggG v-layout component-major: v_in[k][c] = agg[64 + c*64 + k] (k-contiguous)
__global__ __launch_bounds__(256, 3)
void mlp_kernel(const float* __restrict__ aggG,
                const float* __restrict__ As,
                const float* __restrict__ Av,
                const float* __restrict__ Bs,
                const float* __restrict__ Bv,
                float* __restrict__ xs,
                float* __restrict__ xv) {
    __shared__ float aggL[16][256];
    __shared__ float outL[64][128];
    int t = threadIdx.x;
    int a0 = blockIdx.x * 16;
    {
        const float4* g4 = (const float4*)(aggG + (size_t)a0*256);
        float4* l4 = (float4*)&aggL[0][0];
        #pragma unroll
        for (int it = 0; it < 4; it++) l4[it*256 + t] = g4[it*256 + t];
    }
    __syncthreads();

    int q  = t & 31;
    int rp = t >> 5;
    const float4* As4 = (const float4*)As;
    const float4* Av4 = (const float4*)Av;
    const float4* Bs4 = (const float4*)Bs;
    const float4* Bv4 = (const float4*)Bv;

    int ra[6], rc[6];
    #pragma unroll
    for (int i = 0; i < 6; i++) {
        int rv = rp + 8*i;
        ra[i] = rv/3; rc[i] = rv - 3*(rv/3);
    }

    // ---- stage 1 s: os1 rows rp, rp+8 ----
    {
        float ox0=0,oy0=0,oz0=0,ow0=0, ox1=0,oy1=0,oz1=0,ow1=0;
        const float4* x0p = (const float4*)&aggL[rp][0];
        const float4* x1p = (const float4*)&aggL[rp+8][0];
        #pragma unroll 4
        for (int kq = 0; kq < 16; kq++) {
            float4 x0 = x0p[kq], x1 = x1p[kq];
            float4 wa = As4[(4*kq+0)*32 + q];
            float4 wb = As4[(4*kq+1)*32 + q];
            float4 wc = As4[(4*kq+2)*32 + q];
            float4 wd = As4[(4*kq+3)*32 + q];
            ox0 += x0.x*wa.x + x0.y*wb.x + x0.z*wc.x + x0.w*wd.x;
            oy0 += x0.x*wa.y + x0.y*wb.y + x0.z*wc.y + x0.w*wd.y;
            oz0 += x0.x*wa.z + x0.y*wb.z + x0.z*wc.z + x0.w*wd.z;
            ow0 += x0.x*wa.w + x0.y*wb.w + x0.z*wc.w + x0.w*wd.w;
            ox1 += x1.x*wa.x + x1.y*wb.x + x1.z*wc.x + x1.w*wd.x;
            oy1 += x1.x*wa.y + x1.y*wb.y + x1.z*wc.y + x1.w*wd.y;
            oz1 += x1.x*wa.z + x1.y*wb.z + x1.z*wc.z + x1.w*wd.z;
            ow1 += x1.x*wa.w + x1.y*wb.w + x1.z*wc.w + x1.w*wd.w;
        }
        float4 r0 = { ssp(ox0*INV_SQRT_2NF), ssp(oy0*INV_SQRT_2NF), ssp(oz0*INV_SQRT_2NF), ssp(ow0*INV_SQRT_2NF) };
        float4 r1 = { ssp(ox1*INV_SQRT_2NF), ssp(oy1*INV_SQRT_2NF), ssp(oz1*INV_SQRT_2NF), ssp(ow1*INV_SQRT_2NF) };
        *(float4*)&outL[rp][4*q]   = r0;
        *(float4*)&outL[rp+8][4*q] = r1;
    }
    // ---- stage 1 v: ov1 rows 16+rp+8i ----
    {
        float o[6][4];
        #pragma unroll
        for (int i = 0; i < 6; i++) { o[i][0]=0; o[i][1]=0; o[i][2]=0; o[i][3]=0; }
        const float4* vp[6];
        #pragma unroll
        for (int i = 0; i < 6; i++)
            vp[i] = (const float4*)&aggL[ra[i]][64 + rc[i]*64];
        #pragma unroll 2
        for (int kq = 0; kq < 16; kq++) {
            float4 wa = Av4[(4*kq+0)*32 + q];
            float4 wb = Av4[(4*kq+1)*32 + q];
            float4 wc = Av4[(4*kq+2)*32 + q];
            float4 wd = Av4[(4*kq+3)*32 + q];
            #pragma unroll
            for (int i = 0; i < 6; i++) {
                float4 x = vp[i][kq];
                o[i][0] += x.x*wa.x + x.y*wb.x + x.z*wc.x + x.w*wd.x;
                o[i][1] += x.x*wa.y + x.y*wb.y + x.z*wc.y + x.w*wd.y;
                o[i][2] += x.x*wa.z + x.y*wb.z + x.z*wc.z + x.w*wd.z;
                o[i][3] += x.x*wa.w + x.y*wb.w + x.z*wc.w + x.w*wd.w;
            }
        }
        #pragma unroll
        for (int i = 0; i < 6; i++) {
            float4 r = { o[i][0]*INV_SQRT_2NF, o[i][1]*INV_SQRT_2NF, o[i][2]*INV_SQRT_2NF, o[i][3]*INV_SQRT_2NF };
            *(float4*)&outL[16 + rp + 8*i][4*q] = r;
        }
    }
    __syncthreads();
    // ---- stage 2 s: xs += os1 @ Bs ----
    {
        float ox0=0,oy0=0,oz0=0,ow0=0, ox1=0,oy1=0,oz1=0,ow1=0;
        const float4* x0p = (const float4*)&outL[rp][0];
        const float4* x1p = (const float4*)&outL[rp+8][0];
        #pragma unroll 4
        for (int kq = 0; kq < 32; kq++) {
            float4 x0 = x0p[kq], x1 = x1p[kq];
            float4 wa = Bs4[(4*kq+0)*32 + q];
            float4 wb = Bs4[(4*kq+1)*32 + q];
            float4 wc = Bs4[(4*kq+2)*32 + q];
            float4 wd = Bs4[(4*kq+3)*32 + q];
            ox0 += x0.x*wa.x + x0.y*wb.x + x0.z*wc.x + x0.w*wd.x;
            oy0 += x0.x*wa.y + x0.y*wb.y + x0.z*wc.y + x0.w*wd.y;
            oz0 += x0.x*wa.z + x0.y*wb.z + x0.z*wc.z + x0.w*wd.z;
            ow0 += x0.x*wa.w + x0.y*wb.w + x0.z*wc.w + x0.w*wd.w;
            ox1 += x1.x*wa.x + x1.y*wb.x + x1.z*wc.x + x1.w*wd.x;
            oy1 += x1.x*wa.y + x1.y*wb.y + x1.z*wc.y + x1.w*wd.y;
            oz1 += x1.x*wa.z + x1.y*wb.z + x1.z*wc.z + x1.w*wd.z;
            ow1 += x1.x*wa.w + x1.y*wb.w + x1.z*wc.w + x1.w*wd.w;
        }
        float4* p0 = (float4*)&xs[(size_t)(a0+rp)*128 + 4*q];
        float4* p1 = (float4*)&xs[(size_t)(a0+rp+8)*128 + 4*q];
        float4 c0 = *p0, c1 = *p1;
        c0.x += ox0*INV_SQRT_F; c0.y += oy0*INV_SQRT_F; c0.z += oz0*INV_SQRT_F; c0.w += ow0*INV_SQRT_F;
        c1.x += ox1*INV_SQRT_F; c1.y += oy1*INV_SQRT_F; c1.z += oz1*INV_SQRT_F; c1.w += ow1*INV_SQRT_F;
        *p0 = c0; *p1 = c1;
    }
    // ---- stage 2 v: xv += ov1 @ Bv ----
    {
        float o[6][4];
        #pragma unroll
        for (int i = 0; i < 6; i++) { o[i][0]=0; o[i][1]=0; o[i][2]=0; o[i][3]=0; }
        const float4* vp[6];
        #pragma unroll
        for (int i = 0; i < 6; i++)
            vp[i] = (const float4*)&outL[16 + rp + 8*i][0];
        #pragma unroll 2
        for (int kq = 0; kq < 32; kq++) {
            float4 wa = Bv4[(4*kq+0)*32 + q];
            float4 wb = Bv4[(4*kq+1)*32 + q];
            float4 wc = Bv4[(4*kq+2)*32 + q];
            float4 wd = Bv4[(4*kq+3)*32 + q];
            #pragma unroll
            for (int i = 0; i < 6; i++) {
                float4 x = vp[i][kq];
                o[i][0] += x.x*wa.x + x.y*wb.x + x.z*wc.x + x.w*wd.x;
                o[i][1] += x.x*wa.y + x.y*wb.y + x.z*wc.y + x.w*wd.y;
                o[i][2] += x.x*wa.z + x.y*wb.z + x.z*wc.z + x.w*wd.z;
                o[i][3] += x.x*wa.w + x.y*wb.w + x.z*wc.w + x.w*wd.w;
            }
        }
        #pragma unroll
        for (int i = 0; i < 6; i++) {
            float4* p = (float4*)&xv[(size_t)(a0+ra[i])*384 + rc[i]*128 + 4*q];
            float4 c = *p;
            c.x += o[i][0]*INV_SQRT_F; c.y += o[i][1]*INV_SQRT_F;
            c.z += o[i][2]*INV_SQRT_F; c.w += o[i][3]*INV_SQRT_F;
            *p = c;
        }
    }
}

// ----------------------------------------------------------------
extern "C" void kernel_launch(void* const* d_in, const int* in_sizes, int n_in,
                              void* d_out, int out_size, void* d_ws, size_t ws_size,
                              hipStream_t stream) {
    (void)in_sizes; (void)n_in; (void)out_size; (void)ws_size;
    const int*   Z     = (const int*)  d_in[0];
    const float* r_ij  = (const float*)d_in[1];
    const int*   idx_i = (const int*)  d_in[2];
    const int*   idx_j = (const int*)  d_in[3];
    const float* emb   = (const float*)d_in[4];
    const float* Wpe   = (const float*)d_in[5];
    const float* W0s   = (const float*)d_in[6];
    const float* W0v   = (const float*)d_in[7];
    const float* Wf1   = (const float*)d_in[8];
    const float* bf1   = (const float*)d_in[9];
    const float* Wf2   = (const float*)d_in[10];
    const float* bf2   = (const float*)d_in[11];
    const float* As    = (const float*)d_in[12];
    const float* Av    = (const float*)d_in[13];
    const float* Bs    = (const float*)d_in[14];
    const float* Bv    = (const float*)d_in[15];

    float* xs = (float*)d_out;
    float* ws = (float*)d_ws;
    float* fijT = ws;                      // NE*20
    float* yvrT = fijT + (size_t)NE*NRBF;  // NE*4
    float* xv   = yvrT + (size_t)NE*4;     // NA*384  ([n][3][128])
    float* hsv  = xv   + (size_t)NA*F*3;   // NA*128
    float* aggG = hsv  + (size_t)NA*F;     // NA*256
    float* Wf2T = aggG + (size_t)NA*256;   // 3*128*32

    hipMemsetAsync(xv, 0, (size_t)NA*F*3*sizeof(float), stream);

    geom_kernel<<<(NE+255)/256, 256, 0, stream>>>(r_ij, fijT, yvrT);
    prep_kernel<<<(3*128*32+255)/256, 256, 0, stream>>>(Wf2, Wf2T);
    embed_kernel<<<NA/32, 256, 0, stream>>>(Z, emb, Wpe, xs);

    for (int l = 0; l < 3; l++) {
        h_kernel<<<NA/16, 256, 0, stream>>>(xs, xv,
                                            W0s + (size_t)l*F*NF, W0v + (size_t)l*F*NF,
                                            hsv);
        hipMemsetAsync(aggG, 0, (size_t)NA*256*sizeof(float), stream);
        agg_kernel<<<NE/256, 256, 0, stream>>>(idx_i, idx_j, fijT, yvrT, hsv,
                                               Wf1 + (size_t)l*NRBF*NF, bf1 + (size_t)l*NF,
                                               Wf2T + (size_t)l*128*32, bf2 + (size_t)l*6*NF,
                                               aggG);
        mlp_kernel<<<NA/16, 256, 0, stream>>>(aggG,
                                              As + (size_t)l*2*NF*F, Av + (size_t)l*2*NF*F,
                                              Bs + (size_t)l*F*F,    Bv + (size_t)l*F*F,
                                              xs, xv);
    }
}

// Round 9
// 440.366 us; speedup vs baseline: 4.1577x; 1.2042x over previous
//
#include <hip/hip_runtime.h>
#include <math.h>

constexpr int NA   = 16000;
constexpr int NE   = 256000;
constexpr int F    = 128;
constexpr int NF   = 32;
constexpr int NRBF = 20;
constexpr float CUTOFF       = 5.0f;
constexpr float INV_SQRT_F   = 0.0883883476483184f;  // 1/sqrt(128)
constexpr float INV_SQRT_2NF = 0.125f;               // 1/sqrt(64)
constexpr float INV_SQ3      = 0.5773502691896258f;
constexpr float SQ3          = 1.7320508075688772f;
constexpr float LOG2_        = 0.6931471805599453f;
constexpr float PI_          = 3.14159265358979323f;

__device__ __forceinline__ float ssp(float x) {
    return fmaxf(x, 0.0f) + __logf(1.0f + __expf(-fabsf(x))) - LOG2_;
}
__device__ __forceinline__ float rlane_f(float v, int l) {
    return __int_as_float(__builtin_amdgcn_readlane(__float_as_int(v), l));
}

// ---------------------------------------------------------------- K0: per-edge geometry (transposed outputs)
__global__ void geom_kernel(const float* __restrict__ r_ij,
                            float* __restrict__ fijT,
                            float* __restrict__ yvrT) {
    int e = blockIdx.x * blockDim.x + threadIdx.x;
    if (e >= NE) return;
    float x = r_ij[3*e+0], y = r_ij[3*e+1], z = r_ij[3*e+2];
    float d = sqrtf(x*x + y*y + z*z);
    const float delta = CUTOFF / (NRBF - 1);
    const float coeff = -0.5f / (delta * delta);
    #pragma unroll
    for (int k = 0; k < NRBF; k++) {
        float t = d - delta * (float)k;
        fijT[(size_t)k*NE + e] = __expf(coeff * t * t);
    }
    float rc = 0.5f * (__cosf(PI_ * d / CUTOFF) + 1.0f);
    rc = (d < CUTOFF) ? rc : 0.0f;
    float inv = SQ3 / fmaxf(d, 1e-9f);
    yvrT[0*(size_t)NE + e] = x * inv;
    yvrT[1*(size_t)NE + e] = y * inv;
    yvrT[2*(size_t)NE + e] = z * inv;
    yvrT[3*(size_t)NE + e] = rc;
}

// ---------------------------------------------------------------- prep: Wf2T[l][c][k] = Wf2[l][k][c], c<128
__global__ void prep_kernel(const float* __restrict__ Wf2, float* __restrict__ Wf2T) {
    int u = blockIdx.x * 256 + threadIdx.x;
    if (u >= 3*128*32) return;
    int l = u >> 12, rem = u & 4095, c = rem >> 5, k = rem & 31;
    Wf2T[u] = Wf2[(size_t)l*NF*192 + k*192 + c];
}

// ---------------------------------------------------------------- prep2: AvBv[l][f][c] = (Av[l]@Bv[l]) * scale
__global__ void prep2_kernel(const float* __restrict__ Av, const float* __restrict__ Bv,
                             float* __restrict__ AvBv) {
    int u = blockIdx.x * 256 + threadIdx.x;
    if (u >= 3*64*128) return;
    int l = u >> 13, rem = u & 8191, f = rem >> 7, c = rem & 127;
    const float* av = Av + (size_t)l*64*128 + f*128;
    const float* bv = Bv + (size_t)l*128*128 + c;
    float acc = 0.f;
    #pragma unroll 8
    for (int g = 0; g < 128; g++) acc += av[g] * bv[(size_t)g*128];
    AvBv[u] = acc * (INV_SQRT_2NF * INV_SQRT_F);
}

// ---------------------------------------------------------------- K2: xs = emb[Z] @ W_pe (32 atoms/block)
__global__ __launch_bounds__(256, 4)
void embed_kernel(const int* __restrict__ Z,
                  const float* __restrict__ emb,
                  const float* __restrict__ Wpe,
                  float* __restrict__ xs) {
    __shared__ float ER[32][128];
    __shared__ int   Zs[32];
    int t = threadIdx.x;
    int a0 = blockIdx.x * 32;
    if (t < 32) Zs[t] = Z[a0 + t];
    __syncthreads();
    {
        const float4* emb4 = (const float4*)emb;
        float4* ER4 = (float4*)&ER[0][0];
        #pragma unroll
        for (int it = 0; it < 4; it++) {
            int u4 = it*256 + t;
            int a = u4 >> 5, k4 = u4 & 31;
            ER4[u4] = emb4[(size_t)Zs[a]*32 + k4];
        }
    }
    __syncthreads();
    int c = t & 127, half = t >> 7;
    float acc[16];
    #pragma unroll
    for (int a = 0; a < 16; a++) acc[a] = 0.f;
    for (int k = 0; k < 128; k++) {
        float w = Wpe[k*128 + c];
        #pragma unroll
        for (int a = 0; a < 16; a++) acc[a] += ER[half*16 + a][k] * w;
    }
    #pragma unroll
    for (int a = 0; a < 16; a++)
        xs[(size_t)(a0 + half*16 + a)*128 + c] = acc[a] * INV_SQRT_F;
}

// ---------------------------------------------------------------- K3: hsv projection (16 atoms/block)
// hsv[n][128]: [0..31] = hs, [32 + g*3 + c] = hv ; xv layout [n][3][128]
template <bool XV_ZERO>
__global__ __launch_bounds__(256, 4)
void h_kernel(const float* __restrict__ xs,
              const float* __restrict__ xv,
              const float* __restrict__ W0s,
              const float* __restrict__ W0v,
              float* __restrict__ hsv) {
    __shared__ float X[16][512];
    int t = threadIdx.x;
    int a0 = blockIdx.x * 16;
    {
        float* Xf = &X[0][0];
        const float4* xs4 = (const float4*)xs;
        #pragma unroll
        for (int it = 0; it < 2; it++) {
            int u4 = it*256 + t;
            int a = u4 >> 5, k4 = u4 & 31;
            *(float4*)&Xf[a*512 + k4*4] = xs4[(size_t)a0*32 + u4];
        }
        if (!XV_ZERO) {
            const float4* xv4 = (const float4*)xv;
            #pragma unroll
            for (int it = 0; it < 6; it++) {
                int u4 = it*256 + t;
                int a = u4 / 96, rem = u4 - a*96;
                *(float4*)&Xf[a*512 + 128 + rem*4] = xv4[(size_t)a0*96 + u4];
            }
        }
    }
    __syncthreads();
    int g = t & 31, r = t >> 5;
    int sel = r & 3, half = r >> 2;
    if (XV_ZERO && sel != 0) {
        #pragma unroll
        for (int a = 0; a < 8; a++) {
            int n = a0 + half*8 + a;
            hsv[(size_t)n*128 + 32 + g*3 + (sel-1)] = 0.f;
        }
        return;
    }
    const float* W = (sel == 0) ? W0s : W0v;
    int xoff = (sel == 0) ? 0 : (128 + (sel-1)*128);
    float acc[8];
    #pragma unroll
    for (int a = 0; a < 8; a++) acc[a] = 0.f;
    for (int k = 0; k < 128; k++) {
        float w = W[k*32 + g];
        #pragma unroll
        for (int a = 0; a < 8; a++) acc[a] += X[half*8 + a][xoff + k] * w;
    }
    #pragma unroll
    for (int a = 0; a < 8; a++) {
        int n = a0 + half*8 + a;
        if (sel == 0) hsv[(size_t)n*128 + g] = acc[a] * INV_SQRT_F;
        else          hsv[(size_t)n*128 + 32 + g*3 + (sel-1)] = acc[a] * INV_SQRT_F;
    }
}

// ---------------------------------------------------------------- K4: edge aggregation, 64 edges/wave
// aggG row (256): [0..63] s-cols; [64 + c*64 + f] = v_in[f][c].
template <bool DO_V>
__global__ __launch_bounds__(256, 3)
void agg_kernel(const int* __restrict__ idx_i,
                const int* __restrict__ idx_j,
                const float* __restrict__ fijT,
                const float* __restrict__ yvrT,
                const float* __restrict__ hsv,
                const float* __restrict__ Wf1,
                const float* __restrict__ bf1,
                const float* __restrict__ Wf2T,
                const float* __restrict__ bf2,
                float* __restrict__ aggG) {
    __shared__ float LWf1[NRBF*NF];     // 2560 B
    __shared__ float HB[4][64][36];     // 36864 B
    int t = threadIdx.x;
    for (int u = t; u < NRBF*NF; u += 256) LWf1[u] = Wf1[u];
    __syncthreads();

    int wid = t >> 6, lane = t & 63;
    int base = (blockIdx.x*4 + wid) * 64;

    int   il = idx_i[base + lane];
    int   jl = idx_j[base + lane];
    float y0l = yvrT[0*(size_t)NE + base + lane];
    float y1l = yvrT[1*(size_t)NE + base + lane];
    float y2l = yvrT[2*(size_t)NE + base + lane];
    float y3l = yvrT[3*(size_t)NE + base + lane];

    int ilp = __shfl_up(il, 1);
    unsigned long long bmask = __ballot(lane > 0 && il != ilp);

    // ---- MLP1, lane-per-edge ----
    float h[32];
    #pragma unroll
    for (int g = 0; g < 32; g++) h[g] = bf1[g];
    #pragma unroll
    for (int k = 0; k < NRBF; k++) {
        float fk = fijT[(size_t)k*NE + base + lane];
        #pragma unroll
        for (int q = 0; q < 8; q++) {
            float4 w = *(const float4*)&LWf1[k*32 + q*4];
            h[q*4+0] += fk * w.x;
            h[q*4+1] += fk * w.y;
            h[q*4+2] += fk * w.z;
            h[q*4+3] += fk * w.w;
        }
    }
    #pragma unroll
    for (int g = 0; g < 32; g++) h[g] = ssp(h[g]);
    #pragma unroll
    for (int q = 0; q < 8; q++) {
        float4 v = { h[q*4], h[q*4+1], h[q*4+2], h[q*4+3] };
        *(float4*)&HB[wid][lane][q*4] = v;
    }

    // ---- per-lane weights ----
    float4 w2a[8], w2b[8];
    #pragma unroll
    for (int q = 0; q < 8; q++) w2a[q] = *(const float4*)&Wf2T[lane*32 + q*4];
    if (DO_V) {
        #pragma unroll
        for (int q = 0; q < 8; q++) w2b[q] = *(const float4*)&Wf2T[(64+lane)*32 + q*4];
    }
    float bf2a = bf2[lane];
    float bf2b = DO_V ? bf2[64 + lane] : 0.f;

    int idxQ = 32 + 3*(lane - 32);

    float a0 = 0.f, a1 = 0.f, a2 = 0.f, a3 = 0.f;
    int prev = __builtin_amdgcn_readlane(il, 0);
    const float* hb = &HB[wid][0][0];

    for (int ii = 0; ii < 64; ++ii) {
        if ((bmask >> ii) & 1ull) {
            unsafeAtomicAdd(&aggG[(size_t)prev*256 + lane], a0);
            a0 = 0.f;
            if (DO_V) {
                unsafeAtomicAdd(&aggG[(size_t)prev*256 + 64 + lane],  a1);
                unsafeAtomicAdd(&aggG[(size_t)prev*256 + 128 + lane], a2);
                unsafeAtomicAdd(&aggG[(size_t)prev*256 + 192 + lane], a3);
                a1 = a2 = a3 = 0.f;
            }
            prev = __builtin_amdgcn_readlane(il, ii);
        }
        int j = __builtin_amdgcn_readlane(jl, ii);
        const float* row = hsv + (size_t)j*128;
        float q0, q1, q2;
        if (lane < 32) {
            q0 = row[lane]; q1 = q0; q2 = q0;
        } else {
            const float* p = row + idxQ;
            q0 = p[0]; q1 = p[1]; q2 = p[2];
        }
        float s0 = bf2a, s1 = bf2b;
        const float* hrow = hb + ii*36;
        #pragma unroll
        for (int qq = 0; qq < 8; qq++) {
            float4 hq = *(const float4*)&hrow[qq*4];
            s0 += hq.x*w2a[qq].x + hq.y*w2a[qq].y + hq.z*w2a[qq].z + hq.w*w2a[qq].w;
            if (DO_V)
                s1 += hq.x*w2b[qq].x + hq.y*w2b[qq].y + hq.z*w2b[qq].z + hq.w*w2b[qq].w;
        }
        float y3s = rlane_f(y3l, ii);
        float y0s = rlane_f(y0l, ii);
        float y1s = rlane_f(y1l, ii);
        float y2s = rlane_f(y2l, ii);
        float w0 = s0 * y3s;
        float dot = (q0*y0s + q1*y1s + q2*y2s) * INV_SQ3;
        float v0 = (lane < 32) ? q0 : dot;
        a0 += v0 * w0;
        if (DO_V) {
            float w1 = s1 * y3s;
            float m1 = (lane < 32) ? y0s : 1.0f;
            float m2 = (lane < 32) ? y1s : 1.0f;
            float m3 = (lane < 32) ? y2s : 1.0f;
            a1 += q0 * m1 * w1;
            a2 += q1 * m2 * w1;
            a3 += q2 * m3 * w1;
        }
    }
    unsafeAtomicAdd(&aggG[(size_t)prev*256 + lane], a0);
    if (DO_V) {
        unsafeAtomicAdd(&aggG[(size_t)prev*256 + 64 + lane],  a1);
        unsafeAtomicAdd(&aggG[(size_t)prev*256 + 128 + lane], a2);
        unsafeAtomicAdd(&aggG[(size_t)prev*256 + 192 + lane], a3);
    }
}

// ---------------------------------------------------------------- K5: batched atom-side MLP
// s path: os1=ssp(s_in@As*inv); xs += os1@Bs*inv.  v path: xv (+)= v_in @ AvBv (prescaled).
template <bool DO_V, bool XV_WRITE>
__global__ __launch_bounds__(256, 4)
void mlp_kernel(const float* __restrict__ aggG,
                const float* __restrict__ As,
                const float* __restrict__ Bs,
                const float* __restrict__ AvBv,
                float* __restrict__ xs,
                float* __restrict__ xv) {
    constexpr int AC = DO_V ? 256 : 64;
    __shared__ float aggL[16][AC];
    __shared__ float outL[16][128];
    int t = threadIdx.x;
    int a0 = blockIdx.x * 16;
    {
        const float4* g4 = (const float4*)(aggG + (size_t)a0*256);
        if (DO_V) {
            #pragma unroll
            for (int it = 0; it < 4; it++) {
                int u4 = it*256 + t;
                *(float4*)&aggL[0][u4*4 - (u4>>6)*(256-AC)*0] = g4[u4];  // AC==256 here
            }
        } else {
            int row = t >> 4, c4 = t & 15;
            *(float4*)&aggL[row][c4*4] = g4[row*64 + c4];
        }
    }
    __syncthreads();

    int q  = t & 31;
    int rp = t >> 5;
    const float4* As4 = (const float4*)As;
    const float4* Bs4 = (const float4*)Bs;

    // ---- stage 1 s ----
    {
        float ox0=0,oy0=0,oz0=0,ow0=0, ox1=0,oy1=0,oz1=0,ow1=0;
        const float4* x0p = (const float4*)&aggL[rp][0];
        const float4* x1p = (const float4*)&aggL[rp+8][0];
        #pragma unroll 4
        for (int kq = 0; kq < 16; kq++) {
            float4 x0 = x0p[kq], x1 = x1p[kq];
            float4 wa = As4[(4*kq+0)*32 + q];
            float4 wb = As4[(4*kq+1)*32 + q];
            float4 wc = As4[(4*kq+2)*32 + q];
            float4 wd = As4[(4*kq+3)*32 + q];
            ox0 += x0.x*wa.x + x0.y*wb.x + x0.z*wc.x + x0.w*wd.x;
            oy0 += x0.x*wa.y + x0.y*wb.y + x0.z*wc.y + x0.w*wd.y;
            oz0 += x0.x*wa.z + x0.y*wb.z + x0.z*wc.z + x0.w*wd.z;
            ow0 += x0.x*wa.w + x0.y*wb.w + x0.z*wc.w + x0.w*wd.w;
            ox1 += x1.x*wa.x + x1.y*wb.x + x1.z*wc.x + x1.w*wd.x;
            oy1 += x1.x*wa.y + x1.y*wb.y + x1.z*wc.y + x1.w*wd.y;
            oz1 += x1.x*wa.z + x1.y*wb.z + x1.z*wc.z + x1.w*wd.z;
            ow1 += x1.x*wa.w + x1.y*wb.w + x1.z*wc.w + x1.w*wd.w;
        }
        float4 r0 = { ssp(ox0*INV_SQRT_2NF), ssp(oy0*INV_SQRT_2NF), ssp(oz0*INV_SQRT_2NF), ssp(ow0*INV_SQRT_2NF) };
        float4 r1 = { ssp(ox1*INV_SQRT_2NF), ssp(oy1*INV_SQRT_2NF), ssp(oz1*INV_SQRT_2NF), ssp(ow1*INV_SQRT_2NF) };
        *(float4*)&outL[rp][4*q]   = r0;
        *(float4*)&outL[rp+8][4*q] = r1;
    }
    // ---- v path: xv (+)= v_in @ AvBv ----
    if (DO_V) {
        const float4* AB4 = (const float4*)AvBv;
        int ra[6], rc[6];
        #pragma unroll
        for (int i = 0; i < 6; i++) {
            int rv = rp + 8*i;
            ra[i] = rv/3; rc[i] = rv - 3*(rv/3);
        }
        float o[6][4];
        #pragma unroll
        for (int i = 0; i < 6; i++) { o[i][0]=0; o[i][1]=0; o[i][2]=0; o[i][3]=0; }
        const float4* vp[6];
        #pragma unroll
        for (int i = 0; i < 6; i++)
            vp[i] = (const float4*)&aggL[ra[i]][64 + rc[i]*64];
        #pragma unroll 2
        for (int kq = 0; kq < 16; kq++) {
            float4 wa = AB4[(4*kq+0)*32 + q];
            float4 wb = AB4[(4*kq+1)*32 + q];
            float4 wc = AB4[(4*kq+2)*32 + q];
            float4 wd = AB4[(4*kq+3)*32 + q];
            #pragma unroll
            for (int i = 0; i < 6; i++) {
                float4 x = vp[i][kq];
                o[i][0] += x.x*wa.x + x.y*wb.x + x.z*wc.x + x.w*wd.x;
                o[i][1] += x.x*wa.y + x.y*wb.y + x.z*wc.y + x.w*wd.y;
                o[i][2] += x.x*wa.z + x.y*wb.z + x.z*wc.z + x.w*wd.z;
                o[i][3] += x.x*wa.w + x.y*wb.w + x.z*wc.w + x.w*wd.w;
            }
        }
        #pragma unroll
        for (int i = 0; i < 6; i++) {
            float4* p = (float4*)&xv[(size_t)(a0+ra[i])*384 + rc[i]*128 + 4*q];
            if (XV_WRITE) {
                float4 c = { o[i][0], o[i][1], o[i][2], o[i][3] };
                *p = c;
            } else {
                float4 c = *p;
                c.x += o[i][0]; c.y += o[i][1]; c.z += o[i][2]; c.w += o[i][3];
                *p = c;
            }
        }
    }
    __syncthreads();
    // ---- stage 2 s: xs += os1 @ Bs ----
    {
        float ox0=0,oy0=0,oz0=0,ow0=0, ox1=0,oy1=0,oz1=0,ow1=0;
        const float4* x0p = (const float4*)&outL[rp][0];
        const float4* x1p = (const float4*)&outL[rp+8][0];
        #pragma unroll 4
        for (int kq = 0; kq < 32; kq++) {
            float4 x0 = x0p[kq], x1 = x1p[kq];
            float4 wa = Bs4[(4*kq+0)*32 + q];
            float4 wb = Bs4[(4*kq+1)*32 + q];
            float4 wc = Bs4[(4*kq+2)*32 + q];
            float4 wd = Bs4[(4*kq+3)*32 + q];
            ox0 += x0.x*wa.x + x0.y*wb.x + x0.z*wc.x + x0.w*wd.x;
            oy0 += x0.x*wa.y + x0.y*wb.y + x0.z*wc.y + x0.w*wd.y;
            oz0 += x0.x*wa.z + x0.y*wb.z + x0.z*wc.z + x0.w*wd.z;
            ow0 += x0.x*wa.w + x0.y*wb.w + x0.z*wc.w + x0.w*wd.w;
            ox1 += x1.x*wa.x + x1.y*wb.x + x1.z*wc.x + x1.w*wd.x;
            oy1 += x1.x*wa.y + x1.y*wb.y + x1.z*wc.y + x1.w*wd.y;
            oz1 += x1.x*wa.z + x1.y*wb.z + x1.z*wc.z + x1.w*wd.z;
            ow1 += x1.x*wa.w + x1.y*wb.w + x1.z*wc.w + x1.w*wd.w;
        }
        float4* p0 = (float4*)&xs[(size_t)(a0+rp)*128 + 4*q];
        float4* p1 = (float4*)&xs[(size_t)(a0+rp+8)*128 + 4*q];
        float4 c0 = *p0, c1 = *p1;
        c0.x += ox0*INV_SQRT_F; c0.y += oy0*INV_SQRT_F; c0.z += oz0*INV_SQRT_F; c0.w += ow0*INV_SQRT_F;
        c1.x += ox1*INV_SQRT_F; c1.y += oy1*INV_SQRT_F; c1.z += oz1*INV_SQRT_F; c1.w += ow1*INV_SQRT_F;
        *p0 = c0; *p1 = c1;
    }
}

// ----------------------------------------------------------------
extern "C" void kernel_launch(void* const* d_in, const int* in_sizes, int n_in,
                              void* d_out, int out_size, void* d_ws, size_t ws_size,
                              hipStream_t stream) {
    (void)in_sizes; (void)n_in; (void)out_size; (void)ws_size;
    const int*   Z     = (const int*)  d_in[0];
    const float* r_ij  = (const float*)d_in[1];
    const int*   idx_i = (const int*)  d_in[2];
    const int*   idx_j = (const int*)  d_in[3];
    const float* emb   = (const float*)d_in[4];
    const float* Wpe   = (const float*)d_in[5];
    const float* W0s   = (const float*)d_in[6];
    const float* W0v   = (const float*)d_in[7];
    const float* Wf1   = (const float*)d_in[8];
    const float* bf1   = (const float*)d_in[9];
    const float* Wf2   = (const float*)d_in[10];
    const float* bf2   = (const float*)d_in[11];
    const float* As    = (const float*)d_in[12];
    const float* Av    = (const float*)d_in[13];
    const float* Bs    = (const float*)d_in[14];
    const float* Bv    = (const float*)d_in[15];

    float* xs = (float*)d_out;
    float* ws = (float*)d_ws;
    float* fijT = ws;                      // NE*20
    float* yvrT = fijT + (size_t)NE*NRBF;  // NE*4
    float* xv   = yvrT + (size_t)NE*4;     // NA*384  ([n][3][128])
    float* hsv  = xv   + (size_t)NA*F*3;   // NA*128
    float* aggG = hsv  + (size_t)NA*F;     // NA*256
    float* Wf2T = aggG + (size_t)NA*256;   // 3*128*32
    float* AvBv = Wf2T + (size_t)3*128*32; // 3*64*128

    geom_kernel<<<(NE+255)/256, 256, 0, stream>>>(r_ij, fijT, yvrT);
    prep_kernel<<<(3*128*32+255)/256, 256, 0, stream>>>(Wf2, Wf2T);
    prep2_kernel<<<(3*64*128+255)/256, 256, 0, stream>>>(Av, Bv, AvBv);
    embed_kernel<<<NA/32, 256, 0, stream>>>(Z, emb, Wpe, xs);

    for (int l = 0; l < 3; l++) {
        if (l == 0)
            h_kernel<true><<<NA/16, 256, 0, stream>>>(xs, xv,
                W0s + (size_t)l*F*NF, W0v + (size_t)l*F*NF, hsv);
        else
            h_kernel<false><<<NA/16, 256, 0, stream>>>(xs, xv,
                W0s + (size_t)l*F*NF, W0v + (size_t)l*F*NF, hsv);

        hipMemsetAsync(aggG, 0, (size_t)NA*256*sizeof(float), stream);

        if (l < 2)
            agg_kernel<true><<<NE/256, 256, 0, stream>>>(idx_i, idx_j, fijT, yvrT, hsv,
                Wf1 + (size_t)l*NRBF*NF, bf1 + (size_t)l*NF,
                Wf2T + (size_t)l*128*32, bf2 + (size_t)l*6*NF, aggG);
        else
            agg_kernel<false><<<NE/256, 256, 0, stream>>>(idx_i, idx_j, fijT, yvrT, hsv,
                Wf1 + (size_t)l*NRBF*NF, bf1 + (size_t)l*NF,
                Wf2T + (size_t)l*128*32, bf2 + (size_t)l*6*NF, aggG);

        if (l == 0)
            mlp_kernel<true, true><<<NA/16, 256, 0, stream>>>(aggG,
                As + (size_t)l*2*NF*F, Bs + (size_t)l*F*F, AvBv + (size_t)l*64*128, xs, xv);
        else if (l == 1)
            mlp_kernel<true, false><<<NA/16, 256, 0, stream>>>(aggG,
                As + (size_t)l*2*NF*F, Bs + (size_t)l*F*F, AvBv + (size_t)l*64*128, xs, xv);
        else
            mlp_kernel<false, false><<<NA/16, 256, 0, stream>>>(aggG,
                As + (size_t)l*2*NF*F, Bs + (size_t)l*F*F, AvBv + (size_t)l*64*128, xs, xv);
    }
}

// Round 10
// 399.993 us; speedup vs baseline: 4.5774x; 1.1009x over previous
//
#include <hip/hip_runtime.h>
#include <math.h>

constexpr int NA   = 16000;
constexpr int NE   = 256000;
constexpr int F    = 128;
constexpr int NF   = 32;
constexpr int NRBF = 20;
constexpr float CUTOFF       = 5.0f;
constexpr float INV_SQRT_F   = 0.0883883476483184f;  // 1/sqrt(128)
constexpr float INV_SQRT_2NF = 0.125f;               // 1/sqrt(64)
constexpr float INV_SQ3      = 0.5773502691896258f;
constexpr float SQ3          = 1.7320508075688772f;
constexpr float LOG2_        = 0.6931471805599453f;
constexpr float PI_          = 3.14159265358979323f;

typedef _Float16 h2 __attribute__((ext_vector_type(2)));

__device__ __forceinline__ float ssp(float x) {
    return fmaxf(x, 0.0f) + __logf(1.0f + __expf(-fabsf(x))) - LOG2_;
}
__device__ __forceinline__ float fdot2(h2 a, h2 b, float c) {
#if __has_builtin(__builtin_amdgcn_fdot2)
    return __builtin_amdgcn_fdot2(a, b, c, false);
#else
    return c + (float)a[0]*(float)b[0] + (float)a[1]*(float)b[1];
#endif
}

// ---------------------------------------------------------------- K0: per-edge geometry (transposed outputs)
__global__ void geom_kernel(const float* __restrict__ r_ij,
                            float* __restrict__ fijT,
                            float* __restrict__ yvrT) {
    int e = blockIdx.x * blockDim.x + threadIdx.x;
    if (e >= NE) return;
    float x = r_ij[3*e+0], y = r_ij[3*e+1], z = r_ij[3*e+2];
    float d = sqrtf(x*x + y*y + z*z);
    const float delta = CUTOFF / (NRBF - 1);
    const float coeff = -0.5f / (delta * delta);
    #pragma unroll
    for (int k = 0; k < NRBF; k++) {
        float t = d - delta * (float)k;
        fijT[(size_t)k*NE + e] = __expf(coeff * t * t);
    }
    float rc = 0.5f * (__cosf(PI_ * d / CUTOFF) + 1.0f);
    rc = (d < CUTOFF) ? rc : 0.0f;
    float inv = SQ3 / fmaxf(d, 1e-9f);
    yvrT[0*(size_t)NE + e] = x * inv;
    yvrT[1*(size_t)NE + e] = y * inv;
    yvrT[2*(size_t)NE + e] = z * inv;
    yvrT[3*(size_t)NE + e] = rc;
}

// ---------------------------------------------------------------- preph: f16 filter weights
// Wf2H[l][c][k2] = {Wf2[l][2k2][c], Wf2[l][2k2+1][c]}  (c < 128)
// Wf1H[l][k2][g] = {Wf1[l][2k2][g], Wf1[l][2k2+1][g]}
__global__ void preph_kernel(const float* __restrict__ Wf2, const float* __restrict__ Wf1,
                             h2* __restrict__ Wf2H, h2* __restrict__ Wf1H) {
    int u = blockIdx.x * 256 + threadIdx.x;
    if (u < 3*128*16) {
        int l = u / (128*16), rem = u % (128*16), c = rem >> 4, k2 = rem & 15;
        const float* W = Wf2 + (size_t)l*NF*192;
        Wf2H[u] = h2{(_Float16)W[(2*k2)*192 + c], (_Float16)W[(2*k2+1)*192 + c]};
    }
    if (u < 3*320) {
        int l = u / 320, rem = u % 320, k2 = rem >> 5, g = rem & 31;
        const float* W = Wf1 + (size_t)l*NRBF*NF;
        Wf1H[u] = h2{(_Float16)W[(2*k2)*32 + g], (_Float16)W[(2*k2+1)*32 + g]};
    }
}

// ---------------------------------------------------------------- prep2: AvBv[l][f][c] = (Av[l]@Bv[l]) * scale
__global__ void prep2_kernel(const float* __restrict__ Av, const float* __restrict__ Bv,
                             float* __restrict__ AvBv) {
    int u = blockIdx.x * 256 + threadIdx.x;
    if (u >= 3*64*128) return;
    int l = u >> 13, rem = u & 8191, f = rem >> 7, c = rem & 127;
    const float* av = Av + (size_t)l*64*128 + f*128;
    const float* bv = Bv + (size_t)l*128*128 + c;
    float acc = 0.f;
    #pragma unroll 8
    for (int g = 0; g < 128; g++) acc += av[g] * bv[(size_t)g*128];
    AvBv[u] = acc * (INV_SQRT_2NF * INV_SQRT_F);
}

// ---------------------------------------------------------------- K2: xs = emb[Z] @ W_pe (32 atoms/block)
__global__ __launch_bounds__(256, 4)
void embed_kernel(const int* __restrict__ Z,
                  const float* __restrict__ emb,
                  const float* __restrict__ Wpe,
                  float* __restrict__ xs) {
    __shared__ float ER[32][128];
    __shared__ int   Zs[32];
    int t = threadIdx.x;
    int a0 = blockIdx.x * 32;
    if (t < 32) Zs[t] = Z[a0 + t];
    __syncthreads();
    {
        const float4* emb4 = (const float4*)emb;
        float4* ER4 = (float4*)&ER[0][0];
        #pragma unroll
        for (int it = 0; it < 4; it++) {
            int u4 = it*256 + t;
            int a = u4 >> 5, k4 = u4 & 31;
            ER4[u4] = emb4[(size_t)Zs[a]*32 + k4];
        }
    }
    __syncthreads();
    int c = t & 127, half = t >> 7;
    float acc[16];
    #pragma unroll
    for (int a = 0; a < 16; a++) acc[a] = 0.f;
    for (int k = 0; k < 128; k++) {
        float w = Wpe[k*128 + c];
        #pragma unroll
        for (int a = 0; a < 16; a++) acc[a] += ER[half*16 + a][k] * w;
    }
    #pragma unroll
    for (int a = 0; a < 16; a++)
        xs[(size_t)(a0 + half*16 + a)*128 + c] = acc[a] * INV_SQRT_F;
}

// ---------------------------------------------------------------- K3: hsv projection (16 atoms/block)
template <bool XV_ZERO>
__global__ __launch_bounds__(256, 4)
void h_kernel(const float* __restrict__ xs,
              const float* __restrict__ xv,
              const float* __restrict__ W0s,
              const float* __restrict__ W0v,
              float* __restrict__ hsv) {
    __shared__ float X[16][512];
    int t = threadIdx.x;
    int a0 = blockIdx.x * 16;
    {
        float* Xf = &X[0][0];
        const float4* xs4 = (const float4*)xs;
        #pragma unroll
        for (int it = 0; it < 2; it++) {
            int u4 = it*256 + t;
            int a = u4 >> 5, k4 = u4 & 31;
            *(float4*)&Xf[a*512 + k4*4] = xs4[(size_t)a0*32 + u4];
        }
        if (!XV_ZERO) {
            const float4* xv4 = (const float4*)xv;
            #pragma unroll
            for (int it = 0; it < 6; it++) {
                int u4 = it*256 + t;
                int a = u4 / 96, rem = u4 - a*96;
                *(float4*)&Xf[a*512 + 128 + rem*4] = xv4[(size_t)a0*96 + u4];
            }
        }
    }
    __syncthreads();
    int g = t & 31, r = t >> 5;
    int sel = r & 3, half = r >> 2;
    if (XV_ZERO && sel != 0) {
        #pragma unroll
        for (int a = 0; a < 8; a++) {
            int n = a0 + half*8 + a;
            hsv[(size_t)n*128 + 32 + g*3 + (sel-1)] = 0.f;
        }
        return;
    }
    const float* W = (sel == 0) ? W0s : W0v;
    int xoff = (sel == 0) ? 0 : (128 + (sel-1)*128);
    float acc[8];
    #pragma unroll
    for (int a = 0; a < 8; a++) acc[a] = 0.f;
    for (int k = 0; k < 128; k++) {
        float w = W[k*32 + g];
        #pragma unroll
        for (int a = 0; a < 8; a++) acc[a] += X[half*8 + a][xoff + k] * w;
    }
    #pragma unroll
    for (int a = 0; a < 8; a++) {
        int n = a0 + half*8 + a;
        if (sel == 0) hsv[(size_t)n*128 + g] = acc[a] * INV_SQRT_F;
        else          hsv[(size_t)n*128 + 32 + g*3 + (sel-1)] = acc[a] * INV_SQRT_F;
    }
}

// ---------------------------------------------------------------- K4: edge aggregation, 64 edges/wave, fdot2
// aggG row (256): [0..63] s-cols; [64 + c*64 + f] = v_in[f][c].
template <bool DO_V>
__global__ __launch_bounds__(256, 6)
void agg_kernel(const int* __restrict__ idx_i,
                const int* __restrict__ idx_j,
                const float* __restrict__ fijT,
                const float* __restrict__ yvrT,
                const float* __restrict__ hsv,
                const h2* __restrict__ Wf1H,
                const float* __restrict__ bf1,
                const h2* __restrict__ Wf2H,
                const float* __restrict__ bf2,
                float* __restrict__ aggG) {
    __shared__ h2 LW1[320];          // 1280 B
    __shared__ h2 HB[4][64][18];     // 18432 B (72B rows: 2-way bank alias = free)
    int t = threadIdx.x;
    for (int u = t; u < 320; u += 256) LW1[u] = Wf1H[u];
    __syncthreads();

    int wid = t >> 6, lane = t & 63;
    int base = (blockIdx.x*4 + wid) * 64;

    int   il = idx_i[base + lane];
    int   jl = idx_j[base + lane];
    float y0l = yvrT[0*(size_t)NE + base + lane];
    float y1l = yvrT[1*(size_t)NE + base + lane];
    float y2l = yvrT[2*(size_t)NE + base + lane];
    float y3l = yvrT[3*(size_t)NE + base + lane];

    int ilp = __shfl_up(il, 1);
    unsigned long long bmask = __ballot(lane > 0 && il != ilp);

    // ---- MLP1, lane-per-edge, fdot2 ----
    h2 fp[10];
    #pragma unroll
    for (int k2 = 0; k2 < 10; k2++) {
        float fa = fijT[(size_t)(2*k2)*NE + base + lane];
        float fb = fijT[(size_t)(2*k2+1)*NE + base + lane];
        fp[k2] = h2{(_Float16)fa, (_Float16)fb};
    }
    float h[32];
    #pragma unroll
    for (int g = 0; g < 32; g++) h[g] = bf1[g];
    #pragma unroll
    for (int k2 = 0; k2 < 10; k2++) {
        #pragma unroll
        for (int g = 0; g < 32; g++)
            h[g] = fdot2(fp[k2], LW1[k2*32 + g], h[g]);
    }
    #pragma unroll
    for (int g = 0; g < 32; g++) h[g] = ssp(h[g]);
    #pragma unroll
    for (int i = 0; i < 16; i++)
        HB[wid][lane][i] = h2{(_Float16)h[2*i], (_Float16)h[2*i+1]};

    // ---- per-lane f16 weight columns (16 VGPRs each) ----
    h2 w2a[16], w2b[16];
    #pragma unroll
    for (int k2 = 0; k2 < 16; k2++) w2a[k2] = Wf2H[lane*16 + k2];
    if (DO_V) {
        #pragma unroll
        for (int k2 = 0; k2 < 16; k2++) w2b[k2] = Wf2H[(64+lane)*16 + k2];
    }
    float bf2a = bf2[lane];
    float bf2b = DO_V ? bf2[64 + lane] : 0.f;

    int idxQ = 32 + 3*(lane - 32);

    float a0 = 0.f, a1 = 0.f, a2 = 0.f, a3 = 0.f;
    int prev = __builtin_amdgcn_readlane(il, 0);

    for (int ii = 0; ii < 64; ++ii) {
        if ((bmask >> ii) & 1ull) {
            unsafeAtomicAdd(&aggG[(size_t)prev*256 + lane], a0);
            a0 = 0.f;
            if (DO_V) {
                unsafeAtomicAdd(&aggG[(size_t)prev*256 + 64 + lane],  a1);
                unsafeAtomicAdd(&aggG[(size_t)prev*256 + 128 + lane], a2);
                unsafeAtomicAdd(&aggG[(size_t)prev*256 + 192 + lane], a3);
                a1 = a2 = a3 = 0.f;
            }
            prev = __builtin_amdgcn_readlane(il, ii);
        }
        int j = __builtin_amdgcn_readlane(jl, ii);
        const float* row = hsv + (size_t)j*128;
        float q0, q1, q2;
        if (lane < 32) {
            q0 = row[lane]; q1 = q0; q2 = q0;
        } else {
            const float* p = row + idxQ;
            q0 = p[0]; q1 = p[1]; q2 = p[2];
        }
        // MLP2: own columns via fdot2 on broadcast h1
        float s0 = bf2a, s1 = bf2b;
        const h2* hrow = &HB[wid][ii][0];
        #pragma unroll
        for (int k2 = 0; k2 < 16; k2++) {
            h2 hq = hrow[k2];
            s0 = fdot2(hq, w2a[k2], s0);
            if (DO_V) s1 = fdot2(hq, w2b[k2], s1);
        }
        float y3s = __int_as_float(__builtin_amdgcn_readlane(__float_as_int(y3l), ii));
        float y0s = __int_as_float(__builtin_amdgcn_readlane(__float_as_int(y0l), ii));
        float y1s = __int_as_float(__builtin_amdgcn_readlane(__float_as_int(y1l), ii));
        float y2s = __int_as_float(__builtin_amdgcn_readlane(__float_as_int(y2l), ii));
        float w0 = s0 * y3s;
        float dot = (q0*y0s + q1*y1s + q2*y2s) * INV_SQ3;
        float v0 = (lane < 32) ? q0 : dot;
        a0 += v0 * w0;
        if (DO_V) {
            float w1 = s1 * y3s;
            float m1 = (lane < 32) ? y0s : 1.0f;
            float m2 = (lane < 32) ? y1s : 1.0f;
            float m3 = (lane < 32) ? y2s : 1.0f;
            a1 += q0 * m1 * w1;
            a2 += q1 * m2 * w1;
            a3 += q2 * m3 * w1;
        }
    }
    unsafeAtomicAdd(&aggG[(size_t)prev*256 + lane], a0);
    if (DO_V) {
        unsafeAtomicAdd(&aggG[(size_t)prev*256 + 64 + lane],  a1);
        unsafeAtomicAdd(&aggG[(size_t)prev*256 + 128 + lane], a2);
        unsafeAtomicAdd(&aggG[(size_t)prev*256 + 192 + lane], a3);
    }
}

// ---------------------------------------------------------------- K5: batched atom-side MLP
template <bool DO_V, bool XV_WRITE>
__global__ __launch_bounds__(256, 4)
void mlp_kernel(const float* __restrict__ aggG,
                const float* __restrict__ As,
                const float* __restrict__ Bs,
                const float* __restrict__ AvBv,
                float* __restrict__ xs,
                float* __restrict__ xv) {
    constexpr int AC = DO_V ? 256 : 64;
    __shared__ float aggL[16][AC];
    __shared__ float outL[16][128];
    int t = threadIdx.x;
    int a0 = blockIdx.x * 16;
    {
        const float4* g4 = (const float4*)(aggG + (size_t)a0*256);
        if (DO_V) {
            float4* l4 = (float4*)&aggL[0][0];
            #pragma unroll
            for (int it = 0; it < 4; it++) l4[it*256 + t] = g4[it*256 + t];
        } else {
            int row = t >> 4, c4 = t & 15;
            *(float4*)&aggL[row][c4*4] = g4[row*64 + c4];
        }
    }
    __syncthreads();

    int q  = t & 31;
    int rp = t >> 5;
    const float4* As4 = (const float4*)As;
    const float4* Bs4 = (const float4*)Bs;

    // ---- stage 1 s ----
    {
        float ox0=0,oy0=0,oz0=0,ow0=0, ox1=0,oy1=0,oz1=0,ow1=0;
        const float4* x0p = (const float4*)&aggL[rp][0];
        const float4* x1p = (const float4*)&aggL[rp+8][0];
        #pragma unroll 4
        for (int kq = 0; kq < 16; kq++) {
            float4 x0 = x0p[kq], x1 = x1p[kq];
            float4 wa = As4[(4*kq+0)*32 + q];
            float4 wb = As4[(4*kq+1)*32 + q];
            float4 wc = As4[(4*kq+2)*32 + q];
            float4 wd = As4[(4*kq+3)*32 + q];
            ox0 += x0.x*wa.x + x0.y*wb.x + x0.z*wc.x + x0.w*wd.x;
            oy0 += x0.x*wa.y + x0.y*wb.y + x0.z*wc.y + x0.w*wd.y;
            oz0 += x0.x*wa.z + x0.y*wb.z + x0.z*wc.z + x0.w*wd.z;
            ow0 += x0.x*wa.w + x0.y*wb.w + x0.z*wc.w + x0.w*wd.w;
            ox1 += x1.x*wa.x + x1.y*wb.x + x1.z*wc.x + x1.w*wd.x;
            oy1 += x1.x*wa.y + x1.y*wb.y + x1.z*wc.y + x1.w*wd.y;
            oz1 += x1.x*wa.z + x1.y*wb.z + x1.z*wc.z + x1.w*wd.z;
            ow1 += x1.x*wa.w + x1.y*wb.w + x1.z*wc.w + x1.w*wd.w;
        }
        float4 r0 = { ssp(ox0*INV_SQRT_2NF), ssp(oy0*INV_SQRT_2NF), ssp(oz0*INV_SQRT_2NF), ssp(ow0*INV_SQRT_2NF) };
        float4 r1 = { ssp(ox1*INV_SQRT_2NF), ssp(oy1*INV_SQRT_2NF), ssp(oz1*INV_SQRT_2NF), ssp(ow1*INV_SQRT_2NF) };
        *(float4*)&outL[rp][4*q]   = r0;
        *(float4*)&outL[rp+8][4*q] = r1;
    }
    // ---- v path: xv (+)= v_in @ AvBv ----
    if (DO_V) {
        const float4* AB4 = (const float4*)AvBv;
        int ra[6], rc[6];
        #pragma unroll
        for (int i = 0; i < 6; i++) {
            int rv = rp + 8*i;
            ra[i] = rv/3; rc[i] = rv - 3*(rv/3);
        }
        float o[6][4];
        #pragma unroll
        for (int i = 0; i < 6; i++) { o[i][0]=0; o[i][1]=0; o[i][2]=0; o[i][3]=0; }
        const float4* vp[6];
        #pragma unroll
        for (int i = 0; i < 6; i++)
            vp[i] = (const float4*)&aggL[ra[i]][64 + rc[i]*64];
        #pragma unroll 2
        for (int kq = 0; kq < 16; kq++) {
            float4 wa = AB4[(4*kq+0)*32 + q];
            float4 wb = AB4[(4*kq+1)*32 + q];
            float4 wc = AB4[(4*kq+2)*32 + q];
            float4 wd = AB4[(4*kq+3)*32 + q];
            #pragma unroll
            for (int i = 0; i < 6; i++) {
                float4 x = vp[i][kq];
                o[i][0] += x.x*wa.x + x.y*wb.x + x.z*wc.x + x.w*wd.x;
                o[i][1] += x.x*wa.y + x.y*wb.y + x.z*wc.y + x.w*wd.y;
                o[i][2] += x.x*wa.z + x.y*wb.z + x.z*wc.z + x.w*wd.z;
                o[i][3] += x.x*wa.w + x.y*wb.w + x.z*wc.w + x.w*wd.w;
            }
        }
        #pragma unroll
        for (int i = 0; i < 6; i++) {
            float4* p = (float4*)&xv[(size_t)(a0+ra[i])*384 + rc[i]*128 + 4*q];
            if (XV_WRITE) {
                float4 c = { o[i][0], o[i][1], o[i][2], o[i][3] };
                *p = c;
            } else {
                float4 c = *p;
                c.x += o[i][0]; c.y += o[i][1]; c.z += o[i][2]; c.w += o[i][3];
                *p = c;
            }
        }
    }
    __syncthreads();
    // ---- stage 2 s: xs += os1 @ Bs ----
    {
        float ox0=0,oy0=0,oz0=0,ow0=0, ox1=0,oy1=0,oz1=0,ow1=0;
        const float4* x0p = (const float4*)&outL[rp][0];
        const float4* x1p = (const float4*)&outL[rp+8][0];
        #pragma unroll 4
        for (int kq = 0; kq < 32; kq++) {
            float4 x0 = x0p[kq], x1 = x1p[kq];
            float4 wa = Bs4[(4*kq+0)*32 + q];
            float4 wb = Bs4[(4*kq+1)*32 + q];
            float4 wc = Bs4[(4*kq+2)*32 + q];
            float4 wd = Bs4[(4*kq+3)*32 + q];
            ox0 += x0.x*wa.x + x0.y*wb.x + x0.z*wc.x + x0.w*wd.x;
            oy0 += x0.x*wa.y + x0.y*wb.y + x0.z*wc.y + x0.w*wd.y;
            oz0 += x0.x*wa.z + x0.y*wb.z + x0.z*wc.z + x0.w*wd.z;
            ow0 += x0.x*wa.w + x0.y*wb.w + x0.z*wc.w + x0.w*wd.w;
            ox1 += x1.x*wa.x + x1.y*wb.x + x1.z*wc.x + x1.w*wd.x;
            oy1 += x1.x*wa.y + x1.y*wb.y + x1.z*wc.y + x1.w*wd.y;
            oz1 += x1.x*wa.z + x1.y*wb.z + x1.z*wc.z + x1.w*wd.z;
            ow1 += x1.x*wa.w + x1.y*wb.w + x1.z*wc.w + x1.w*wd.w;
        }
        float4* p0 = (float4*)&xs[(size_t)(a0+rp)*128 + 4*q];
        float4* p1 = (float4*)&xs[(size_t)(a0+rp+8)*128 + 4*q];
        float4 c0 = *p0, c1 = *p1;
        c0.x += ox0*INV_SQRT_F; c0.y += oy0*INV_SQRT_F; c0.z += oz0*INV_SQRT_F; c0.w += ow0*INV_SQRT_F;
        c1.x += ox1*INV_SQRT_F; c1.y += oy1*INV_SQRT_F; c1.z += oz1*INV_SQRT_F; c1.w += ow1*INV_SQRT_F;
        *p0 = c0; *p1 = c1;
    }
}

// ----------------------------------------------------------------
extern "C" void kernel_launch(void* const* d_in, const int* in_sizes, int n_in,
                              void* d_out, int out_size, void* d_ws, size_t ws_size,
                              hipStream_t stream) {
    (void)in_sizes; (void)n_in; (void)out_size; (void)ws_size;
    const int*   Z     = (const int*)  d_in[0];
    const float* r_ij  = (const float*)d_in[1];
    const int*   idx_i = (const int*)  d_in[2];
    const int*   idx_j = (const int*)  d_in[3];
    const float* emb   = (const float*)d_in[4];
    const float* Wpe   = (const float*)d_in[5];
    const float* W0s   = (const float*)d_in[6];
    const float* W0v   = (const float*)d_in[7];
    const float* Wf1   = (const float*)d_in[8];
    const float* bf1   = (const float*)d_in[9];
    const float* Wf2   = (const float*)d_in[10];
    const float* bf2   = (const float*)d_in[11];
    const float* As    = (const float*)d_in[12];
    const float* Av    = (const float*)d_in[13];
    const float* Bs    = (const float*)d_in[14];
    const float* Bv    = (const float*)d_in[15];

    float* xs = (float*)d_out;
    float* ws = (float*)d_ws;
    float* fijT = ws;                      // NE*20
    float* yvrT = fijT + (size_t)NE*NRBF;  // NE*4
    float* xv   = yvrT + (size_t)NE*4;     // NA*384  ([n][3][128])
    float* hsv  = xv   + (size_t)NA*F*3;   // NA*128
    float* aggG = hsv  + (size_t)NA*F;     // NA*256
    float* AvBv = aggG + (size_t)NA*256;   // 3*64*128
    h2*    Wf2H = (h2*)(AvBv + (size_t)3*64*128);  // 3*128*16 h2
    h2*    Wf1H = Wf2H + (size_t)3*128*16;         // 3*320 h2

    geom_kernel<<<(NE+255)/256, 256, 0, stream>>>(r_ij, fijT, yvrT);
    preph_kernel<<<24, 256, 0, stream>>>(Wf2, Wf1, Wf2H, Wf1H);
    prep2_kernel<<<(3*64*128+255)/256, 256, 0, stream>>>(Av, Bv, AvBv);
    embed_kernel<<<NA/32, 256, 0, stream>>>(Z, emb, Wpe, xs);

    for (int l = 0; l < 3; l++) {
        if (l == 0)
            h_kernel<true><<<NA/16, 256, 0, stream>>>(xs, xv,
                W0s + (size_t)l*F*NF, W0v + (size_t)l*F*NF, hsv);
        else
            h_kernel<false><<<NA/16, 256, 0, stream>>>(xs, xv,
                W0s + (size_t)l*F*NF, W0v + (size_t)l*F*NF, hsv);

        hipMemsetAsync(aggG, 0, (size_t)NA*256*sizeof(float), stream);

        if (l < 2)
            agg_kernel<true><<<NE/256, 256, 0, stream>>>(idx_i, idx_j, fijT, yvrT, hsv,
                Wf1H + (size_t)l*320, bf1 + (size_t)l*NF,
                Wf2H + (size_t)l*128*16, bf2 + (size_t)l*6*NF, aggG);
        else
            agg_kernel<false><<<NE/256, 256, 0, stream>>>(idx_i, idx_j, fijT, yvrT, hsv,
                Wf1H + (size_t)l*320, bf1 + (size_t)l*NF,
                Wf2H + (size_t)l*128*16, bf2 + (size_t)l*6*NF, aggG);

        if (l == 0)
            mlp_kernel<true, true><<<NA/16, 256, 0, stream>>>(aggG,
                As + (size_t)l*2*NF*F, Bs + (size_t)l*F*F, AvBv + (size_t)l*64*128, xs, xv);
        else if (l == 1)
            mlp_kernel<true, false><<<NA/16, 256, 0, stream>>>(aggG,
                As + (size_t)l*2*NF*F, Bs + (size_t)l*F*F, AvBv + (size_t)l*64*128, xs, xv);
        else
            mlp_kernel<false, false><<<NA/16, 256, 0, stream>>>(aggG,
                As + (size_t)l*2*NF*F, Bs + (size_t)l*F*F, AvBv + (size_t)l*64*128, xs, xv);
    }
}